// Round 9
// baseline (893.311 us; speedup 1.0000x reference)
//
#include <hip/hip_runtime.h>
#include <math.h>

#define S_LEN 512
#define DMODEL 256
#define NHEAD 8
#define HDIM 32
#define NLAYER 4
#define NSCALE 4

typedef unsigned short ushortT;
typedef unsigned int uintT;
typedef short bf16x8 __attribute__((ext_vector_type(8)));
typedef float f32x4 __attribute__((ext_vector_type(4)));

enum { F_PE = 1, F_BETA = 2, F_GELU = 4 };

__device__ __forceinline__ float gelu_f(float x) {
    return 0.5f * x * (1.0f + erff(x * 0.70710678118654752440f));
}
__device__ __forceinline__ ushortT f2bf(float f) {
    union { float f; uintT i; } u; u.f = f;
    uintT r = u.i + 0x7FFF + ((u.i >> 16) & 1);   // RNE
    return (ushortT)(r >> 16);
}
__device__ __forceinline__ int swz(int r) { return (r & 3) ^ ((r >> 2) & 3); }

#define GLD16(g, l) \
    __builtin_amdgcn_global_load_lds((const __attribute__((address_space(1))) void*)(g), \
                                     (__attribute__((address_space(3))) void*)(l), 16, 0, 0)

// C[M,N] = op(A[M,K]bf16 @ W[N,K]bf16^T + bias) ; M%BM==0, N%BN==0, K%64==0
// BK=64 staging (half the barrier drains vs BK=32). bf16-only outputs use an
// LDS-repack epilogue (dwordx4 stores); fp32/beta outputs use direct stores.
template<int BM, int BN>
__global__ __launch_bounds__(256) void mfma_gemm(
    const ushortT* __restrict__ A, int lda,
    const ushortT* __restrict__ W, int ldw,
    const float* __restrict__ bias,
    const float* __restrict__ betaC,
    float* __restrict__ out32,
    ushortT* __restrict__ out16,
    int ldc, int K, int flags)
{
    constexpr int MI = BM / 32;
    constexpr int NI = BN / 32;
    __shared__ __align__(16) ushortT Sm[(BM + BN) * 64];
    ushortT* As = Sm;              // BM rows x 64
    ushortT* Bs = Sm + BM * 64;    // BN rows x 64
    const int tid = threadIdx.x;
    const int wave = tid >> 6, lane = tid & 63;
    const int l15 = lane & 15, qd = lane >> 4;
    const int m0 = blockIdx.x * BM, n0 = blockIdx.y * BN;
    const int wm = (wave >> 1) * (BM / 2), wn = (wave & 1) * (BN / 2);

    f32x4 acc[MI][NI];
    #pragma unroll
    for (int i = 0; i < MI; ++i)
        #pragma unroll
        for (int j = 0; j < NI; ++j) acc[i][j] = (f32x4){0.f, 0.f, 0.f, 0.f};

    for (int k0 = 0; k0 < K; k0 += 64) {
        // stage A: BM rows x 8 slots of 8 bf16. slot s of row m holds source
        // chunk kc = ((s&4)^((m&1)<<2)) | ((s&3)^swz(m))  (bank-even layout)
        #pragma unroll
        for (int it = 0; it < BM / 32; ++it) {
            int c = it * 256 + tid;
            int m = c >> 3, s = c & 7;
            int kc = ((s & 4) ^ ((m & 1) << 2)) | ((s & 3) ^ swz(m));
            GLD16(A + (size_t)(m0 + m) * lda + k0 + kc * 8,
                  As + (size_t)(it * 256 + wave * 64) * 8);
        }
        #pragma unroll
        for (int it = 0; it < BN / 32; ++it) {
            int c = it * 256 + tid;
            int n = c >> 3, s = c & 7;
            int kc = ((s & 4) ^ ((n & 1) << 2)) | ((s & 3) ^ swz(n));
            GLD16(W + (size_t)(n0 + n) * ldw + k0 + kc * 8,
                  Bs + (size_t)(it * 256 + wave * 64) * 8);
        }
        __syncthreads();
        #pragma unroll
        for (int kk = 0; kk < 2; ++kk) {
            bf16x8 af[MI], bfr[NI];
            #pragma unroll
            for (int mi = 0; mi < MI; ++mi) {
                int r = wm + mi * 16 + l15;
                int sl = ((kk << 2) ^ ((r & 1) << 2)) | (qd ^ swz(r));
                af[mi] = *(const bf16x8*)(As + r * 64 + sl * 8);
            }
            #pragma unroll
            for (int ni = 0; ni < NI; ++ni) {
                int r = wn + ni * 16 + l15;
                int sl = ((kk << 2) ^ ((r & 1) << 2)) | (qd ^ swz(r));
                bfr[ni] = *(const bf16x8*)(Bs + r * 64 + sl * 8);
            }
            #pragma unroll
            for (int mi = 0; mi < MI; ++mi)
                #pragma unroll
                for (int ni = 0; ni < NI; ++ni)
                    acc[mi][ni] = __builtin_amdgcn_mfma_f32_16x16x32_bf16(
                        af[mi], bfr[ni], acc[mi][ni], 0, 0, 0);
        }
        __syncthreads();
    }

    if (out16 && !out32) {
        // LDS-repack epilogue (bias/gelu only): 32-row chunks
        #pragma unroll
        for (int c0r = 0; c0r < BM; c0r += 32) {
            #pragma unroll
            for (int mi = 0; mi < MI; ++mi) {
                int rowbase = wm + mi * 16;
                if (rowbase < c0r || rowbase >= c0r + 32) continue;
                #pragma unroll
                for (int ni = 0; ni < NI; ++ni) {
                    int col = wn + ni * 16 + l15;
                    float bv = bias ? bias[n0 + col] : 0.f;
                    #pragma unroll
                    for (int r = 0; r < 4; ++r) {
                        int row = rowbase + qd * 4 + r;
                        float v = acc[mi][ni][r] + bv;
                        if (flags & F_GELU) v = gelu_f(v);
                        int sc = col ^ (((row >> 2) & 3) << 4);
                        Sm[(row & 31) * BN + sc] = f2bf(v);
                    }
                }
            }
            __syncthreads();
            constexpr int TPR = BN / 8;        // threads per row
            constexpr int RPP = 256 / TPR;     // rows per pass
            int lrowb = tid / TPR;
            int coff = (tid % TPR) * 8;
            #pragma unroll
            for (int rr = 0; rr < 32; rr += RPP) {
                int lrow = rr + lrowb;
                int sc = coff ^ ((((c0r + lrow) >> 2) & 3) << 4);
                uint4 val = *(const uint4*)&Sm[lrow * BN + sc];
                *(uint4*)(out16 + (size_t)(m0 + c0r + lrow) * ldc + n0 + coff) = val;
            }
            __syncthreads();
        }
    } else {
        #pragma unroll
        for (int mi = 0; mi < MI; ++mi) {
            #pragma unroll
            for (int ni = 0; ni < NI; ++ni) {
                int col = n0 + wn + ni * 16 + l15;
                float bv = bias ? bias[col] : 0.f;
                #pragma unroll
                for (int r = 0; r < 4; ++r) {
                    int grow = m0 + wm + mi * 16 + qd * 4 + r;
                    float v = acc[mi][ni][r] + bv;
                    if (flags & F_BETA) v += betaC[(size_t)grow * ldc + col];
                    if (flags & F_PE) {
                        int pos = grow & (S_LEN - 1);
                        float div = expf((float)(col & ~1) * (-9.210340371976184f / 256.0f));
                        float ang = (float)pos * div;
                        v += (col & 1) ? cosf(ang) : sinf(ang);
                    }
                    if (flags & F_GELU) v = gelu_f(v);
                    if (out32) out32[(size_t)grow * ldc + col] = v;
                    if (out16) out16[(size_t)grow * ldc + col] = f2bf(v);
                }
            }
        }
    }
}

// Batched MFMA for Wcat: for each ls=(l,si):
//   Wcat[l][n][si*256+j] = sum_p fus_w[l][n][si*256+p] * ao_w[ls][p][j]
__global__ __launch_bounds__(256) void wc_mfma(
    const float* __restrict__ fus_w, const float* __restrict__ ao_w,
    ushortT* __restrict__ Wcat)
{
    __shared__ __align__(16) ushortT As[128 * 32];
    __shared__ __align__(16) ushortT Bs[128 * 32];
    const int z = blockIdx.z, l = z >> 2, si = z & 3;
    const int m0 = blockIdx.x * 128, n0 = blockIdx.y * 128;
    const int tid = threadIdx.x;
    const int wave = tid >> 6, lane = tid & 63;
    const int l15 = lane & 15, qd = lane >> 4;
    const int wm = (wave >> 1) * 64, wn = (wave & 1) * 64;
    const float* Abase = fus_w + ((size_t)(l * 256) + m0) * 1024 + si * 256;
    const float* Bbase = ao_w + (size_t)z * 65536;

    f32x4 acc[4][4];
    #pragma unroll
    for (int i = 0; i < 4; ++i)
        #pragma unroll
        for (int j = 0; j < 4; ++j) acc[i][j] = (f32x4){0.f, 0.f, 0.f, 0.f};

    const int am = tid >> 1, ah = tid & 1;
    const int bp = tid >> 3, bj = (tid & 7) * 16;

    for (int k0 = 0; k0 < 256; k0 += 32) {
        #pragma unroll
        for (int j = 0; j < 2; ++j) {
            const float* src = Abase + (size_t)am * 1024 + k0 + ah * 16 + j * 8;
            float4 f0 = *(const float4*)src;
            float4 f1 = *(const float4*)(src + 4);
            int sc = ah * 2 + j;
            ushortT* d = As + am * 32 + (sc ^ swz(am)) * 8;
            ushort4 u0; u0.x = f2bf(f0.x); u0.y = f2bf(f0.y); u0.z = f2bf(f0.z); u0.w = f2bf(f0.w);
            ushort4 u1; u1.x = f2bf(f1.x); u1.y = f2bf(f1.y); u1.z = f2bf(f1.z); u1.w = f2bf(f1.w);
            *(ushort4*)d = u0; *(ushort4*)(d + 4) = u1;
        }
        #pragma unroll
        for (int c = 0; c < 4; ++c) {
            float4 f = *(const float4*)(Bbase + (size_t)(k0 + bp) * 256 + n0 + bj + c * 4);
            float vv[4] = {f.x, f.y, f.z, f.w};
            #pragma unroll
            for (int e = 0; e < 4; ++e) {
                int r = bj + c * 4 + e;
                Bs[r * 32 + (((bp >> 3) ^ swz(r)) * 8) + (bp & 7)] = f2bf(vv[e]);
            }
        }
        __syncthreads();
        bf16x8 af[4], bfr[4];
        #pragma unroll
        for (int mi = 0; mi < 4; ++mi) {
            int r = wm + mi * 16 + l15;
            af[mi] = *(const bf16x8*)(As + r * 32 + (qd ^ swz(r)) * 8);
        }
        #pragma unroll
        for (int ni = 0; ni < 4; ++ni) {
            int r = wn + ni * 16 + l15;
            bfr[ni] = *(const bf16x8*)(Bs + r * 32 + (qd ^ swz(r)) * 8);
        }
        #pragma unroll
        for (int mi = 0; mi < 4; ++mi)
            #pragma unroll
            for (int ni = 0; ni < 4; ++ni)
                acc[mi][ni] = __builtin_amdgcn_mfma_f32_16x16x32_bf16(
                    af[mi], bfr[ni], acc[mi][ni], 0, 0, 0);
        __syncthreads();
    }

    #pragma unroll
    for (int mi = 0; mi < 4; ++mi) {
        #pragma unroll
        for (int ni = 0; ni < 4; ++ni) {
            int col = n0 + wn + ni * 16 + l15;
            #pragma unroll
            for (int r = 0; r < 4; ++r) {
                int row = m0 + wm + mi * 16 + qd * 4 + r;
                Wcat[((size_t)(l * 256) + row) * 1024 + si * 256 + col] =
                    f2bf(acc[mi][ni][r]);
            }
        }
    }
}

// MFMA banded attention, ALL 4 scales per launch.
// qkv: (B*S, 3072) = 4 scales x (q|k|v * 256). Block = (slot, qblk, h, b).
__global__ __launch_bounds__(256) void attn_mfma(
    const ushortT* __restrict__ qkv, ushortT* __restrict__ ocat)
{
    __shared__ __align__(16) ushortT Vt[32 * 216];     // [d][key_local], stride 216
    __shared__ __align__(16) ushortT Pl[4][16 * 168];  // per-wave P, stride 168
    const int bid = blockIdx.x;
    const int sp   = bid & 3;            // scale slot
    const int qblk = (bid >> 2) & 7;
    const int h    = (bid >> 5) & 7;
    const int b    = (bid >> 8) & 15;
    const int RAD[4] = {5, 10, 20, 50};
    const int r = RAD[sp];
    const int lcol = sp * 768;
    const int tid = threadIdx.x;

    const int q0blk = qblk * 64;
    const int t0 = max(0, q0blk - r) >> 4;
    const int t1 = min(S_LEN - 1, q0blk + 63 + r) >> 4;
    const int nstage = (t1 - t0 + 2) * 16;   // +1 zero pad tile
    const int kmax = min(S_LEN - 1, t1 * 16 + 15);

    const ushortT* bbase = qkv + (size_t)(b * S_LEN) * 3072 + lcol;

    for (int idx = tid; idx < nstage * 4; idx += 256) {
        int row = idx >> 2, dch = idx & 3;
        int key = t0 * 16 + row;
        uint4 u = make_uint4(0, 0, 0, 0);
        if (key <= kmax)
            u = *(const uint4*)(bbase + (size_t)key * 3072 + 512 + h * HDIM + dch * 8);
        ushortT* dst = &Vt[(dch * 8) * 216 + row];
        uintT w[4] = {u.x, u.y, u.z, u.w};
        #pragma unroll
        for (int t = 0; t < 4; ++t) {
            dst[(2 * t) * 216]     = (ushortT)(w[t] & 0xffff);
            dst[(2 * t + 1) * 216] = (ushortT)(w[t] >> 16);
        }
    }

    const int wid = tid >> 6, lane = tid & 63;
    const int quad = lane >> 4, l15 = lane & 15;
    ushortT* Pw = Pl[wid];

    {
        uint4 z = make_uint4(0, 0, 0, 0);
        #pragma unroll
        for (int i = 0; i < 6; ++i) {
            int c = lane + i * 64;
            if (c < 336) ((uint4*)Pw)[c] = z;
        }
    }
    __syncthreads();

    const int q0w = q0blk + wid * 16;
    bf16x8 qf = *(const bf16x8*)(bbase + (size_t)(q0w + l15) * 3072 + h * HDIM + quad * 8);

    const int kt0 = max(0, q0w - r) >> 4;
    const int kt1 = min(S_LEN - 1, q0w + 15 + r) >> 4;
    const int nt = kt1 - kt0 + 1;

    f32x4 rs4 = (f32x4){0.f, 0.f, 0.f, 0.f};
    const unsigned span = (unsigned)(2 * r);

    for (int kt = kt0; kt <= kt1; ++kt) {
        int key = kt * 16 + l15;
        bf16x8 kf = *(const bf16x8*)(bbase + (size_t)key * 3072 + 256 + h * HDIM + quad * 8);
        f32x4 s4 = __builtin_amdgcn_mfma_f32_16x16x32_bf16(
            qf, kf, (f32x4){0.f, 0.f, 0.f, 0.f}, 0, 0, 0);
        #pragma unroll
        for (int rg = 0; rg < 4; ++rg) {
            int q = q0w + quad * 4 + rg;
            unsigned dd = (unsigned)(key - q + r);
            float p = (dd <= span)
                      ? __expf(fminf(s4[rg] * 0.17677669529663688f, 80.f)) : 0.f;
            rs4[rg] += p;
            Pw[(quad * 4 + rg) * 168 + (kt - kt0) * 16 + l15] = f2bf(p);
        }
    }

    #pragma unroll
    for (int m = 1; m < 16; m <<= 1) {
        #pragma unroll
        for (int rg = 0; rg < 4; ++rg) rs4[rg] += __shfl_xor(rs4[rg], m, 64);
    }

    f32x4 o0 = (f32x4){0.f, 0.f, 0.f, 0.f};
    f32x4 o1 = (f32x4){0.f, 0.f, 0.f, 0.f};
    const int basek = (kt0 - t0) * 16;
    const int nch = (nt + 1) >> 1;
    for (int c = 0; c < nch; ++c) {
        bf16x8 pa = *(const bf16x8*)(Pw + l15 * 168 + c * 32 + quad * 8);
        bf16x8 v0 = *(const bf16x8*)(&Vt[l15 * 216 + basek + c * 32 + quad * 8]);
        bf16x8 v1 = *(const bf16x8*)(&Vt[(l15 + 16) * 216 + basek + c * 32 + quad * 8]);
        o0 = __builtin_amdgcn_mfma_f32_16x16x32_bf16(pa, v0, o0, 0, 0, 0);
        o1 = __builtin_amdgcn_mfma_f32_16x16x32_bf16(pa, v1, o1, 0, 0, 0);
    }

    #pragma unroll
    for (int rg = 0; rg < 4; ++rg) {
        float inv = 1.0f / rs4[rg];
        int q = q0w + quad * 4 + rg;
        ushortT* op = ocat + ((size_t)(b * S_LEN) + q) * 1024 + sp * DMODEL + h * HDIM;
        op[l15]      = f2bf(o0[rg] * inv);
        op[16 + l15] = f2bf(o1[rg] * inv);
    }
}

// one wave per 256-wide row: out = LN(a) * g + be; dual fp32/bf16 write
__global__ __launch_bounds__(64) void ln_wave(
    const float* __restrict__ a,
    const float* __restrict__ g, const float* __restrict__ be,
    float* __restrict__ o32, ushortT* __restrict__ o16)
{
    const int row = blockIdx.x, lane = threadIdx.x;
    float4 v = *(const float4*)(a + (size_t)row * DMODEL + lane * 4);
    float s = v.x + v.y + v.z + v.w;
    #pragma unroll
    for (int off = 32; off; off >>= 1) s += __shfl_xor(s, off, 64);
    float m = s * (1.0f / DMODEL);
    float dx = v.x - m, dy = v.y - m, dz = v.z - m, dw = v.w - m;
    float s2 = dx * dx + dy * dy + dz * dz + dw * dw;
    #pragma unroll
    for (int off = 32; off; off >>= 1) s2 += __shfl_xor(s2, off, 64);
    float r = rsqrtf(s2 * (1.0f / DMODEL) + 1e-5f);
    float4 gg = *(const float4*)(g + lane * 4);
    float4 bb = *(const float4*)(be + lane * 4);
    float y0 = dx * r * gg.x + bb.x, y1 = dy * r * gg.y + bb.y;
    float y2 = dz * r * gg.z + bb.z, y3 = dw * r * gg.w + bb.w;
    *(float4*)(o32 + (size_t)row * DMODEL + lane * 4) = make_float4(y0, y1, y2, y3);
    ushort4 u; u.x = f2bf(y0); u.y = f2bf(y1); u.z = f2bf(y2); u.w = f2bf(y3);
    *(ushort4*)(o16 + (size_t)row * DMODEL + lane * 4) = u;
}

// merged small precompute: ip_w cvt + 3 weight transposes
__global__ __launch_bounds__(256) void prep_misc(
    const float* __restrict__ ip_w, ushortT* __restrict__ ipw_bf,
    const float* __restrict__ feat_w, float* __restrict__ featwT,
    const float* __restrict__ h1_w, float* __restrict__ h1wT,
    const float* __restrict__ h2_w, float* __restrict__ h2wT)
{
    int i = blockIdx.x * 256 + threadIdx.x;
    if (i < 40960) {
        float4 f = ((const float4*)ip_w)[i];
        ushort4 u; u.x = f2bf(f.x); u.y = f2bf(f.y); u.z = f2bf(f.z); u.w = f2bf(f.w);
        ((ushort4*)ipw_bf)[i] = u;
        return;
    }
    int j = i - 40960;
    if (j < 16896) {
        int r = j / 66, c = j - r * 66;
        featwT[(size_t)c * 256 + r] = feat_w[j];
        return;
    }
    j -= 16896;
    if (j < 131072) {
        int r = j >> 9, c = j & 511;
        h1wT[(size_t)c * 256 + r] = h1_w[j];
        return;
    }
    j -= 131072;
    if (j < 32768) {
        int r = j >> 8, c = j & 255;
        h2wT[(size_t)c * 128 + r] = h2_w[j];
    }
}

// Whole head, 16 blocks (one per batch row) x 256 thr; weights pre-transposed.
__global__ __launch_bounds__(256) void head_kernel(
    const float* __restrict__ x32, const float* __restrict__ features,
    const float* __restrict__ feat_wT, const float* __restrict__ feat_b,
    const float* __restrict__ feat_ln_g, const float* __restrict__ feat_ln_b,
    const float* __restrict__ h1_wT, const float* __restrict__ h1_b,
    const float* __restrict__ h_ln_g, const float* __restrict__ h_ln_b,
    const float* __restrict__ h2_wT, const float* __restrict__ h2_b,
    const float* __restrict__ h3_w, const float* __restrict__ h3_b,
    float* __restrict__ outp)
{
    __shared__ float xcat[512];
    __shared__ float h1s[256];
    __shared__ float red[8];
    __shared__ float r2[128];
    const int r = blockIdx.x, t = threadIdx.x;
    const int wid = t >> 6, lane = t & 63;

    xcat[t] = x32[((size_t)r * S_LEN + S_LEN / 2) * DMODEL + t];

    const float* frow = features + (size_t)r * 66;
    float s = feat_b[t];
    for (int k = 0; k < 66; ++k) s = fmaf(frow[k], feat_wT[k * 256 + t], s);
    {
        float a = s, a2 = s * s;
        #pragma unroll
        for (int off = 32; off; off >>= 1) { a += __shfl_xor(a, off, 64); a2 += __shfl_xor(a2, off, 64); }
        if (lane == 0) { red[wid] = a; red[wid + 4] = a2; }
        __syncthreads();
        float ts = red[0] + red[1] + red[2] + red[3];
        float ts2 = red[4] + red[5] + red[6] + red[7];
        float m = ts * (1.0f / 256.0f);
        float var = ts2 * (1.0f / 256.0f) - m * m;
        float rstd = rsqrtf(var + 1e-5f);
        float v = (s - m) * rstd * feat_ln_g[t] + feat_ln_b[t];
        xcat[256 + t] = gelu_f(v);
        __syncthreads();
    }

    s = h1_b[t];
    #pragma unroll 8
    for (int k = 0; k < 512; ++k) s = fmaf(xcat[k], h1_wT[k * 256 + t], s);
    {
        float a = s, a2 = s * s;
        #pragma unroll
        for (int off = 32; off; off >>= 1) { a += __shfl_xor(a, off, 64); a2 += __shfl_xor(a2, off, 64); }
        if (lane == 0) { red[wid] = a; red[wid + 4] = a2; }
        __syncthreads();
        float ts = red[0] + red[1] + red[2] + red[3];
        float ts2 = red[4] + red[5] + red[6] + red[7];
        float m = ts * (1.0f / 256.0f);
        float var = ts2 * (1.0f / 256.0f) - m * m;
        float rstd = rsqrtf(var + 1e-5f);
        float v = (s - m) * rstd * h_ln_g[t] + h_ln_b[t];
        h1s[t] = gelu_f(v);
        __syncthreads();
    }

    if (t < 128) {
        float v = h2_b[t];
        #pragma unroll 8
        for (int k = 0; k < 256; ++k) v = fmaf(h1s[k], h2_wT[k * 128 + t], v);
        r2[t] = gelu_f(v) * h3_w[t];
    }
    __syncthreads();
    if (t < 64) {
        float p = r2[t] + r2[t + 64];
        #pragma unroll
        for (int off = 32; off; off >>= 1) p += __shfl_xor(p, off, 64);
        if (t == 0) outp[r] = p + h3_b[0];
    }
}

__global__ __launch_bounds__(256) void cvt_kernel(
    const float4* __restrict__ src, ushort4* __restrict__ dst, int n4)
{
    int i = blockIdx.x * 256 + threadIdx.x;
    if (i < n4) {
        float4 f = src[i];
        ushort4 u; u.x = f2bf(f.x); u.y = f2bf(f.y); u.z = f2bf(f.z); u.w = f2bf(f.w);
        dst[i] = u;
    }
}

__global__ __launch_bounds__(256) void qkvbias_kernel(
    const float* __restrict__ aib, const float* __restrict__ aiw,
    const float* __restrict__ se, float* __restrict__ eb)
{
    int i = blockIdx.x * 256 + threadIdx.x;   // < 12288
    int r = i % 3072, si = r / 768;
    const float* w = aiw + (size_t)i * 256;
    const float* s = se + si * 256;
    float acc = aib[i];
    for (int k = 0; k < 256; ++k) acc = fmaf(s[k], w[k], acc);
    eb[i] = acc;
}

__global__ __launch_bounds__(256) void fusbias_kernel(
    const float* __restrict__ fus_b, const float* __restrict__ fus_w,
    const float* __restrict__ aob, float* __restrict__ fb)
{
    int l = blockIdx.x, n = threadIdx.x;
    const float* w = fus_w + ((size_t)l * 256 + n) * 1024;
    const float* o = aob + (size_t)l * 1024;
    float acc = fus_b[l * 256 + n];
    for (int j = 0; j < 1024; ++j) acc = fmaf(o[j], w[j], acc);
    fb[l * 256 + n] = acc;
}

static inline void mgemm(hipStream_t s, const ushortT* A, int lda, const ushortT* W, int ldw,
                         const float* bias, const float* betaC, float* o32, ushortT* o16,
                         int ldc, int M, int N, int K, int flags)
{
    if (N >= 3072) {
        dim3 g(M / 128, N / 128);
        hipLaunchKernelGGL((mfma_gemm<128, 128>), g, dim3(256), 0, s,
                           A, lda, W, ldw, bias, betaC, o32, o16, ldc, K, flags);
    } else if (N >= 1024) {
        dim3 g(M / 64, N / 128);
        hipLaunchKernelGGL((mfma_gemm<64, 128>), g, dim3(256), 0, s,
                           A, lda, W, ldw, bias, betaC, o32, o16, ldc, K, flags);
    } else {
        dim3 g(M / 64, N / 64);
        hipLaunchKernelGGL((mfma_gemm<64, 64>), g, dim3(256), 0, s,
                           A, lda, W, ldw, bias, betaC, o32, o16, ldc, K, flags);
    }
}

static inline void cvt(hipStream_t s, const float* src, ushortT* dst, size_t n)
{
    int n4 = (int)(n / 4);
    hipLaunchKernelGGL(cvt_kernel, dim3((n4 + 255) / 256), dim3(256), 0, s,
                       (const float4*)src, (ushort4*)dst, n4);
}

extern "C" void kernel_launch(void* const* d_in, const int* in_sizes, int n_in,
                              void* d_out, int out_size, void* d_ws, size_t ws_size,
                              hipStream_t stream)
{
    const float* emb        = (const float*)d_in[0];
    const float* features   = (const float*)d_in[1];
    const float* ip_w       = (const float*)d_in[2];
    const float* ip_b       = (const float*)d_in[3];
    const float* scale_emb  = (const float*)d_in[4];
    const float* attn_in_w  = (const float*)d_in[5];
    const float* attn_in_b  = (const float*)d_in[6];
    const float* attn_out_w = (const float*)d_in[7];
    const float* attn_out_b = (const float*)d_in[8];
    const float* fus_w      = (const float*)d_in[9];
    const float* fus_b      = (const float*)d_in[10];
    const float* ffn_w1     = (const float*)d_in[11];
    const float* ffn_b1     = (const float*)d_in[12];
    const float* ffn_w2     = (const float*)d_in[13];
    const float* ffn_b2     = (const float*)d_in[14];
    const float* n1_g       = (const float*)d_in[15];
    const float* n1_b       = (const float*)d_in[16];
    const float* n2_g       = (const float*)d_in[17];
    const float* n2_b       = (const float*)d_in[18];
    const float* feat_w     = (const float*)d_in[19];
    const float* feat_b     = (const float*)d_in[20];
    const float* feat_ln_g  = (const float*)d_in[21];
    const float* feat_ln_b  = (const float*)d_in[22];
    const float* h1_w       = (const float*)d_in[23];
    const float* h1_b       = (const float*)d_in[24];
    const float* h_ln_g     = (const float*)d_in[25];
    const float* h_ln_b     = (const float*)d_in[26];
    const float* h2_w       = (const float*)d_in[27];
    const float* h2_b       = (const float*)d_in[28];
    const float* h3_w       = (const float*)d_in[29];
    const float* h3_b       = (const float*)d_in[30];
    float* outp = (float*)d_out;

    const int Btok = 16 * S_LEN;   // 8192

    // ---- workspace carve-up ----
    char* p = (char*)d_ws;
    float* x32     = (float*)p;              p += (size_t)Btok * DMODEL * 4;
    float* fused32 = (float*)p;              p += (size_t)Btok * DMODEL * 4;
    float* effqkvb = (float*)p;              p += 12288 * 4;
    float* fusbias = (float*)p;              p += 1024 * 4;
    float* featwT  = (float*)p;              p += 66 * 256 * 4;
    float* h1wT    = (float*)p;              p += 512 * 256 * 4;
    float* h2wT    = (float*)p;              p += 256 * 128 * 4;
    ushortT* xbf   = (ushortT*)p;            p += (size_t)Btok * DMODEL * 2;
    ushortT* qkv4  = (ushortT*)p;            p += (size_t)Btok * 3072 * 2;   // all 4 scales
    ushortT* ocat  = (ushortT*)p;            p += (size_t)Btok * 1024 * 2;
    ushortT* ipw_bf  = (ushortT*)p;          p += (size_t)DMODEL * 640 * 2;
    ushortT* aiw_bf  = (ushortT*)p;          p += (size_t)16 * 768 * 256 * 2;
    ushortT* wcat_bf = (ushortT*)p;          p += (size_t)4 * 256 * 1024 * 2;
    ushortT* f1_bf   = (ushortT*)p;          p += (size_t)4 * 1024 * 256 * 2;
    ushortT* f2_bf   = (ushortT*)p;          p += (size_t)4 * 256 * 1024 * 2;
    ushortT* embbf = qkv4;                   // alias: emb_bf dead before layer-0 qkv
    ushortT* midbf = ocat;                   // alias: ffn mid after ocat consumed

    // ---- precompute ----
    cvt(stream, emb, embbf, (size_t)Btok * 640);
    cvt(stream, attn_in_w, aiw_bf, (size_t)16 * 768 * 256);
    cvt(stream, ffn_w1, f1_bf, (size_t)4 * 1024 * 256);
    cvt(stream, ffn_w2, f2_bf, (size_t)4 * 256 * 1024);
    hipLaunchKernelGGL(prep_misc, dim3(866), dim3(256), 0, stream,
                       ip_w, ipw_bf, feat_w, featwT, h1_w, h1wT, h2_w, h2wT);
    hipLaunchKernelGGL(wc_mfma, dim3(2, 2, 16), dim3(256), 0, stream,
                       fus_w, attn_out_w, wcat_bf);
    hipLaunchKernelGGL(qkvbias_kernel, dim3(48), dim3(256), 0, stream,
                       attn_in_b, attn_in_w, scale_emb, effqkvb);
    hipLaunchKernelGGL(fusbias_kernel, dim3(4), dim3(256), 0, stream,
                       fus_b, fus_w, attn_out_b, fusbias);

    // ---- x = emb @ ip_w^T + ip_b + PE ----
    mgemm(stream, embbf, 640, ipw_bf, 640, ip_b, nullptr, x32, xbf,
          DMODEL, Btok, DMODEL, 640, F_PE);

    for (int l = 0; l < NLAYER; ++l) {
        // qkv for ALL 4 scales: N=3072, one launch
        mgemm(stream, xbf, DMODEL, aiw_bf + (size_t)l * 3072 * 256, DMODEL,
              effqkvb + (size_t)l * 3072, nullptr, nullptr, qkv4,
              3072, Btok, 3072, DMODEL, 0);
        hipLaunchKernelGGL(attn_mfma, dim3(4096), dim3(256), 0, stream, qkv4, ocat);
        // fused32 = x + ocat @ Wcat[l]^T + fusbias[l]
        mgemm(stream, ocat, 1024, wcat_bf + (size_t)l * 256 * 1024, 1024,
              fusbias + l * DMODEL, x32, fused32, nullptr,
              DMODEL, Btok, DMODEL, 1024, F_BETA);
        hipLaunchKernelGGL(ln_wave, dim3(Btok), dim3(64), 0, stream,
                           fused32, n1_g + l * DMODEL, n1_b + l * DMODEL, x32, xbf);
        mgemm(stream, xbf, DMODEL, f1_bf + (size_t)l * 1024 * 256, DMODEL,
              ffn_b1 + (size_t)l * 1024, nullptr, nullptr, midbf,
              1024, Btok, 1024, DMODEL, F_GELU);
        // fused32 = x + mid @ ffn2^T + b2
        mgemm(stream, midbf, 1024, f2_bf + (size_t)l * 256 * 1024, 1024,
              ffn_b2 + (size_t)l * DMODEL, x32, fused32, nullptr,
              DMODEL, Btok, DMODEL, 1024, F_BETA);
        hipLaunchKernelGGL(ln_wave, dim3(Btok), dim3(64), 0, stream,
                           fused32, n2_g + l * DMODEL, n2_b + l * DMODEL, x32, xbf);
    }

    // ---- head ----
    hipLaunchKernelGGL(head_kernel, dim3(16), dim3(256), 0, stream,
                       x32, features, featwT, feat_b, feat_ln_g, feat_ln_b,
                       h1wT, h1_b, h_ln_g, h_ln_b, h2wT, h2_b, h3_w, h3_b, outp);
}

// Round 10
// 809.400 us; speedup vs baseline: 1.1037x; 1.1037x over previous
//
#include <hip/hip_runtime.h>
#include <math.h>

#define S_LEN 512
#define DMODEL 256
#define NHEAD 8
#define HDIM 32
#define NLAYER 4
#define NSCALE 4

typedef unsigned short ushortT;
typedef unsigned int uintT;
typedef short bf16x8 __attribute__((ext_vector_type(8)));
typedef float f32x4 __attribute__((ext_vector_type(4)));

enum { F_PE = 1, F_BETA = 2, F_GELU = 4 };

__device__ __forceinline__ float gelu_f(float x) {
    return 0.5f * x * (1.0f + erff(x * 0.70710678118654752440f));
}
__device__ __forceinline__ ushortT f2bf(float f) {
    union { float f; uintT i; } u; u.f = f;
    uintT r = u.i + 0x7FFF + ((u.i >> 16) & 1);   // RNE
    return (ushortT)(r >> 16);
}
__device__ __forceinline__ int swz(int r) { return (r & 3) ^ ((r >> 2) & 3); }

#define GLD16(g, l) \
    __builtin_amdgcn_global_load_lds((const __attribute__((address_space(1))) void*)(g), \
                                     (__attribute__((address_space(3))) void*)(l), 16, 0, 0)

// C[M,N] = op(A[M,K]bf16 @ W[N,K]bf16^T + bias) ; M%BM==0, N%BN==0, K%32==0
// (R8 version: BK=32, 16KB LDS — best measured occupancy/time)
template<int BM, int BN>
__global__ __launch_bounds__(256) void mfma_gemm(
    const ushortT* __restrict__ A, int lda,
    const ushortT* __restrict__ W, int ldw,
    const float* __restrict__ bias,
    const float* __restrict__ betaC,
    float* __restrict__ out32,
    ushortT* __restrict__ out16,
    int ldc, int K, int flags)
{
    constexpr int MI = BM / 32;
    constexpr int NI = BN / 32;
    __shared__ __align__(16) ushortT As[BM * 32];
    __shared__ __align__(16) ushortT Bs[BN * 32];
    const int tid = threadIdx.x;
    const int wave = tid >> 6, lane = tid & 63;
    const int l15 = lane & 15, qd = lane >> 4;
    const int m0 = blockIdx.x * BM, n0 = blockIdx.y * BN;
    const int wm = (wave >> 1) * (BM / 2), wn = (wave & 1) * (BN / 2);

    f32x4 acc[MI][NI];
    #pragma unroll
    for (int i = 0; i < MI; ++i)
        #pragma unroll
        for (int j = 0; j < NI; ++j) acc[i][j] = (f32x4){0.f, 0.f, 0.f, 0.f};

    for (int k0 = 0; k0 < K; k0 += 32) {
        #pragma unroll
        for (int it = 0; it < BM / 64; ++it) {
            int c = it * 256 + tid;
            int m = c >> 2, s = c & 3;
            int kc = s ^ swz(m);
            GLD16(A + (size_t)(m0 + m) * lda + k0 + kc * 8,
                  (ushortT*)As + (size_t)(it * 256 + wave * 64) * 8);
        }
        #pragma unroll
        for (int it = 0; it < BN / 64; ++it) {
            int c = it * 256 + tid;
            int n = c >> 2, s = c & 3;
            int kc = s ^ swz(n);
            GLD16(W + (size_t)(n0 + n) * ldw + k0 + kc * 8,
                  (ushortT*)Bs + (size_t)(it * 256 + wave * 64) * 8);
        }
        __syncthreads();
        bf16x8 af[MI], bfr[NI];
        #pragma unroll
        for (int mi = 0; mi < MI; ++mi) {
            int r = wm + mi * 16 + l15;
            af[mi] = *(const bf16x8*)(As + r * 32 + (qd ^ swz(r)) * 8);
        }
        #pragma unroll
        for (int ni = 0; ni < NI; ++ni) {
            int r = wn + ni * 16 + l15;
            bfr[ni] = *(const bf16x8*)(Bs + r * 32 + (qd ^ swz(r)) * 8);
        }
        #pragma unroll
        for (int mi = 0; mi < MI; ++mi)
            #pragma unroll
            for (int ni = 0; ni < NI; ++ni)
                acc[mi][ni] = __builtin_amdgcn_mfma_f32_16x16x32_bf16(
                    af[mi], bfr[ni], acc[mi][ni], 0, 0, 0);
        __syncthreads();
    }

    #pragma unroll
    for (int mi = 0; mi < MI; ++mi) {
        #pragma unroll
        for (int ni = 0; ni < NI; ++ni) {
            int col = n0 + wn + ni * 16 + l15;
            float bv = bias ? bias[col] : 0.f;
            #pragma unroll
            for (int r = 0; r < 4; ++r) {
                int grow = m0 + wm + mi * 16 + qd * 4 + r;
                float v = acc[mi][ni][r] + bv;
                if (flags & F_BETA) v += betaC[(size_t)grow * ldc + col];
                if (flags & F_PE) {
                    int pos = grow & (S_LEN - 1);
                    float div = expf((float)(col & ~1) * (-9.210340371976184f / 256.0f));
                    float ang = (float)pos * div;
                    v += (col & 1) ? cosf(ang) : sinf(ang);
                }
                if (flags & F_GELU) v = gelu_f(v);
                if (out32) out32[(size_t)grow * ldc + col] = v;
                if (out16) out16[(size_t)grow * ldc + col] = f2bf(v);
            }
        }
    }
}

// Full-row GEMM + fused LayerNorm. Tile 16 rows x 256 cols (all of N), K=1024.
//   pre[m,n] = A[m,:]@W[n,:]^T + bias[n] + betaC[m,n]
//   y = LN_row(pre) * g + be ;  writes o32 (fp32, may alias betaC) + o16 (bf16)
__global__ __launch_bounds__(256) void gemm_ln(
    const ushortT* __restrict__ A,          // (M,1024) bf16
    const ushortT* __restrict__ W,          // (256,1024) bf16
    const float* __restrict__ bias,
    const float* __restrict__ betaC,        // (M,256) fp32 residual
    const float* __restrict__ g, const float* __restrict__ be,
    float* __restrict__ o32, ushortT* __restrict__ o16)
{
    __shared__ __align__(16) ushortT As[16 * 32];
    __shared__ __align__(16) ushortT Bs[256 * 32];
    __shared__ float redS[64], redQ[64];
    const int tid = threadIdx.x;
    const int wave = tid >> 6, lane = tid & 63;
    const int l15 = lane & 15, qd = lane >> 4;
    const int m0 = blockIdx.x * 16;

    f32x4 acc[4];
    #pragma unroll
    for (int j = 0; j < 4; ++j) acc[j] = (f32x4){0.f, 0.f, 0.f, 0.f};

    for (int k0 = 0; k0 < 1024; k0 += 32) {
        if (wave == 0) {                      // A: 16 rows x 4 slots
            int m = lane >> 2, s = lane & 3;
            int kc = s ^ swz(m);
            GLD16(A + (size_t)(m0 + m) * 1024 + k0 + kc * 8, (ushortT*)As);
        }
        #pragma unroll
        for (int it = 0; it < 4; ++it) {      // B: 256 rows x 4 slots
            int c = it * 256 + tid;
            int n = c >> 2, s = c & 3;
            int kc = s ^ swz(n);
            GLD16(W + (size_t)n * 1024 + k0 + kc * 8,
                  (ushortT*)Bs + (size_t)(it * 256 + wave * 64) * 8);
        }
        __syncthreads();
        bf16x8 af = *(const bf16x8*)(As + l15 * 32 + (qd ^ swz(l15)) * 8);
        #pragma unroll
        for (int ni = 0; ni < 4; ++ni) {
            int n = wave * 64 + ni * 16 + l15;
            bf16x8 bfr = *(const bf16x8*)(Bs + n * 32 + (qd ^ swz(n)) * 8);
            acc[ni] = __builtin_amdgcn_mfma_f32_16x16x32_bf16(af, bfr, acc[ni], 0, 0, 0);
        }
        __syncthreads();
    }

    // epilogue: bias + residual, then row LN
    float v[4][4];                             // [ni][rg]
    #pragma unroll
    for (int ni = 0; ni < 4; ++ni) {
        int col = wave * 64 + ni * 16 + l15;
        float bv = bias[col];
        #pragma unroll
        for (int rg = 0; rg < 4; ++rg) {
            int row = qd * 4 + rg;
            v[ni][rg] = acc[ni][rg] + bv + betaC[(size_t)(m0 + row) * 256 + col];
        }
    }
    float sr[4], sq[4];
    #pragma unroll
    for (int rg = 0; rg < 4; ++rg) {
        sr[rg] = v[0][rg] + v[1][rg] + v[2][rg] + v[3][rg];
        sq[rg] = v[0][rg] * v[0][rg] + v[1][rg] * v[1][rg]
               + v[2][rg] * v[2][rg] + v[3][rg] * v[3][rg];
    }
    #pragma unroll
    for (int m = 1; m < 16; m <<= 1) {
        #pragma unroll
        for (int rg = 0; rg < 4; ++rg) {
            sr[rg] += __shfl_xor(sr[rg], m, 64);
            sq[rg] += __shfl_xor(sq[rg], m, 64);
        }
    }
    if (l15 == 0) {
        #pragma unroll
        for (int rg = 0; rg < 4; ++rg) {
            redS[wave * 16 + qd * 4 + rg] = sr[rg];
            redQ[wave * 16 + qd * 4 + rg] = sq[rg];
        }
    }
    __syncthreads();
    float mean[4], rstd[4];
    #pragma unroll
    for (int rg = 0; rg < 4; ++rg) {
        int row = qd * 4 + rg;
        float ts = redS[row] + redS[16 + row] + redS[32 + row] + redS[48 + row];
        float tq = redQ[row] + redQ[16 + row] + redQ[32 + row] + redQ[48 + row];
        float m = ts * (1.0f / 256.0f);
        float var = tq * (1.0f / 256.0f) - m * m;
        mean[rg] = m;
        rstd[rg] = rsqrtf(var + 1e-5f);
    }
    #pragma unroll
    for (int ni = 0; ni < 4; ++ni) {
        int col = wave * 64 + ni * 16 + l15;
        float gv = g[col], bev = be[col];
        #pragma unroll
        for (int rg = 0; rg < 4; ++rg) {
            int row = qd * 4 + rg;
            float y = (v[ni][rg] - mean[rg]) * rstd[rg] * gv + bev;
            o32[(size_t)(m0 + row) * 256 + col] = y;
            o16[(size_t)(m0 + row) * 256 + col] = f2bf(y);
        }
    }
}

// Batched MFMA for Wcat: for each ls=(l,si):
//   Wcat[l][n][si*256+j] = sum_p fus_w[l][n][si*256+p] * ao_w[ls][p][j]
__global__ __launch_bounds__(256) void wc_mfma(
    const float* __restrict__ fus_w, const float* __restrict__ ao_w,
    ushortT* __restrict__ Wcat)
{
    __shared__ __align__(16) ushortT As[128 * 32];
    __shared__ __align__(16) ushortT Bs[128 * 32];
    const int z = blockIdx.z, l = z >> 2, si = z & 3;
    const int m0 = blockIdx.x * 128, n0 = blockIdx.y * 128;
    const int tid = threadIdx.x;
    const int wave = tid >> 6, lane = tid & 63;
    const int l15 = lane & 15, qd = lane >> 4;
    const int wm = (wave >> 1) * 64, wn = (wave & 1) * 64;
    const float* Abase = fus_w + ((size_t)(l * 256) + m0) * 1024 + si * 256;
    const float* Bbase = ao_w + (size_t)z * 65536;

    f32x4 acc[4][4];
    #pragma unroll
    for (int i = 0; i < 4; ++i)
        #pragma unroll
        for (int j = 0; j < 4; ++j) acc[i][j] = (f32x4){0.f, 0.f, 0.f, 0.f};

    const int am = tid >> 1, ah = tid & 1;
    const int bp = tid >> 3, bj = (tid & 7) * 16;

    for (int k0 = 0; k0 < 256; k0 += 32) {
        #pragma unroll
        for (int j = 0; j < 2; ++j) {
            const float* src = Abase + (size_t)am * 1024 + k0 + ah * 16 + j * 8;
            float4 f0 = *(const float4*)src;
            float4 f1 = *(const float4*)(src + 4);
            int sc = ah * 2 + j;
            ushortT* d = As + am * 32 + (sc ^ swz(am)) * 8;
            ushort4 u0; u0.x = f2bf(f0.x); u0.y = f2bf(f0.y); u0.z = f2bf(f0.z); u0.w = f2bf(f0.w);
            ushort4 u1; u1.x = f2bf(f1.x); u1.y = f2bf(f1.y); u1.z = f2bf(f1.z); u1.w = f2bf(f1.w);
            *(ushort4*)d = u0; *(ushort4*)(d + 4) = u1;
        }
        #pragma unroll
        for (int c = 0; c < 4; ++c) {
            float4 f = *(const float4*)(Bbase + (size_t)(k0 + bp) * 256 + n0 + bj + c * 4);
            float vv[4] = {f.x, f.y, f.z, f.w};
            #pragma unroll
            for (int e = 0; e < 4; ++e) {
                int r = bj + c * 4 + e;
                Bs[r * 32 + (((bp >> 3) ^ swz(r)) * 8) + (bp & 7)] = f2bf(vv[e]);
            }
        }
        __syncthreads();
        bf16x8 af[4], bfr[4];
        #pragma unroll
        for (int mi = 0; mi < 4; ++mi) {
            int r = wm + mi * 16 + l15;
            af[mi] = *(const bf16x8*)(As + r * 32 + (qd ^ swz(r)) * 8);
        }
        #pragma unroll
        for (int ni = 0; ni < 4; ++ni) {
            int r = wn + ni * 16 + l15;
            bfr[ni] = *(const bf16x8*)(Bs + r * 32 + (qd ^ swz(r)) * 8);
        }
        #pragma unroll
        for (int mi = 0; mi < 4; ++mi)
            #pragma unroll
            for (int ni = 0; ni < 4; ++ni)
                acc[mi][ni] = __builtin_amdgcn_mfma_f32_16x16x32_bf16(
                    af[mi], bfr[ni], acc[mi][ni], 0, 0, 0);
        __syncthreads();
    }

    #pragma unroll
    for (int mi = 0; mi < 4; ++mi) {
        #pragma unroll
        for (int ni = 0; ni < 4; ++ni) {
            int col = n0 + wn + ni * 16 + l15;
            #pragma unroll
            for (int r = 0; r < 4; ++r) {
                int row = m0 + wm + mi * 16 + qd * 4 + r;
                Wcat[((size_t)(l * 256) + row) * 1024 + si * 256 + col] =
                    f2bf(acc[mi][ni][r]);
            }
        }
    }
}

// MFMA banded attention, ALL 4 scales per launch.
// qkv: (B*S, 3072) = 4 scales x (q|k|v * 256). Block = (slot, qblk, h, b).
__global__ __launch_bounds__(256) void attn_mfma(
    const ushortT* __restrict__ qkv, ushortT* __restrict__ ocat)
{
    __shared__ __align__(16) ushortT Vt[32 * 216];     // [d][key_local], stride 216
    __shared__ __align__(16) ushortT Pl[4][16 * 168];  // per-wave P, stride 168
    const int bid = blockIdx.x;
    const int sp   = bid & 3;            // scale slot
    const int qblk = (bid >> 2) & 7;
    const int h    = (bid >> 5) & 7;
    const int b    = (bid >> 8) & 15;
    const int RAD[4] = {5, 10, 20, 50};
    const int r = RAD[sp];
    const int lcol = sp * 768;
    const int tid = threadIdx.x;

    const int q0blk = qblk * 64;
    const int t0 = max(0, q0blk - r) >> 4;
    const int t1 = min(S_LEN - 1, q0blk + 63 + r) >> 4;
    const int nstage = (t1 - t0 + 2) * 16;   // +1 zero pad tile
    const int kmax = min(S_LEN - 1, t1 * 16 + 15);

    const ushortT* bbase = qkv + (size_t)(b * S_LEN) * 3072 + lcol;

    for (int idx = tid; idx < nstage * 4; idx += 256) {
        int row = idx >> 2, dch = idx & 3;
        int key = t0 * 16 + row;
        uint4 u = make_uint4(0, 0, 0, 0);
        if (key <= kmax)
            u = *(const uint4*)(bbase + (size_t)key * 3072 + 512 + h * HDIM + dch * 8);
        ushortT* dst = &Vt[(dch * 8) * 216 + row];
        uintT w[4] = {u.x, u.y, u.z, u.w};
        #pragma unroll
        for (int t = 0; t < 4; ++t) {
            dst[(2 * t) * 216]     = (ushortT)(w[t] & 0xffff);
            dst[(2 * t + 1) * 216] = (ushortT)(w[t] >> 16);
        }
    }

    const int wid = tid >> 6, lane = tid & 63;
    const int quad = lane >> 4, l15 = lane & 15;
    ushortT* Pw = Pl[wid];

    {
        uint4 z = make_uint4(0, 0, 0, 0);
        #pragma unroll
        for (int i = 0; i < 6; ++i) {
            int c = lane + i * 64;
            if (c < 336) ((uint4*)Pw)[c] = z;
        }
    }
    __syncthreads();

    const int q0w = q0blk + wid * 16;
    bf16x8 qf = *(const bf16x8*)(bbase + (size_t)(q0w + l15) * 3072 + h * HDIM + quad * 8);

    const int kt0 = max(0, q0w - r) >> 4;
    const int kt1 = min(S_LEN - 1, q0w + 15 + r) >> 4;
    const int nt = kt1 - kt0 + 1;

    f32x4 rs4 = (f32x4){0.f, 0.f, 0.f, 0.f};
    const unsigned span = (unsigned)(2 * r);

    for (int kt = kt0; kt <= kt1; ++kt) {
        int key = kt * 16 + l15;
        bf16x8 kf = *(const bf16x8*)(bbase + (size_t)key * 3072 + 256 + h * HDIM + quad * 8);
        f32x4 s4 = __builtin_amdgcn_mfma_f32_16x16x32_bf16(
            qf, kf, (f32x4){0.f, 0.f, 0.f, 0.f}, 0, 0, 0);
        #pragma unroll
        for (int rg = 0; rg < 4; ++rg) {
            int q = q0w + quad * 4 + rg;
            unsigned dd = (unsigned)(key - q + r);
            float p = (dd <= span)
                      ? __expf(fminf(s4[rg] * 0.17677669529663688f, 80.f)) : 0.f;
            rs4[rg] += p;
            Pw[(quad * 4 + rg) * 168 + (kt - kt0) * 16 + l15] = f2bf(p);
        }
    }

    #pragma unroll
    for (int m = 1; m < 16; m <<= 1) {
        #pragma unroll
        for (int rg = 0; rg < 4; ++rg) rs4[rg] += __shfl_xor(rs4[rg], m, 64);
    }

    f32x4 o0 = (f32x4){0.f, 0.f, 0.f, 0.f};
    f32x4 o1 = (f32x4){0.f, 0.f, 0.f, 0.f};
    const int basek = (kt0 - t0) * 16;
    const int nch = (nt + 1) >> 1;
    for (int c = 0; c < nch; ++c) {
        bf16x8 pa = *(const bf16x8*)(Pw + l15 * 168 + c * 32 + quad * 8);
        bf16x8 v0 = *(const bf16x8*)(&Vt[l15 * 216 + basek + c * 32 + quad * 8]);
        bf16x8 v1 = *(const bf16x8*)(&Vt[(l15 + 16) * 216 + basek + c * 32 + quad * 8]);
        o0 = __builtin_amdgcn_mfma_f32_16x16x32_bf16(pa, v0, o0, 0, 0, 0);
        o1 = __builtin_amdgcn_mfma_f32_16x16x32_bf16(pa, v1, o1, 0, 0, 0);
    }

    #pragma unroll
    for (int rg = 0; rg < 4; ++rg) {
        float inv = 1.0f / rs4[rg];
        int q = q0w + quad * 4 + rg;
        ushortT* op = ocat + ((size_t)(b * S_LEN) + q) * 1024 + sp * DMODEL + h * HDIM;
        op[l15]      = f2bf(o0[rg] * inv);
        op[16 + l15] = f2bf(o1[rg] * inv);
    }
}

// merged small precompute: ip_w cvt + 3 weight transposes
__global__ __launch_bounds__(256) void prep_misc(
    const float* __restrict__ ip_w, ushortT* __restrict__ ipw_bf,
    const float* __restrict__ feat_w, float* __restrict__ featwT,
    const float* __restrict__ h1_w, float* __restrict__ h1wT,
    const float* __restrict__ h2_w, float* __restrict__ h2wT)
{
    int i = blockIdx.x * 256 + threadIdx.x;
    if (i < 40960) {
        float4 f = ((const float4*)ip_w)[i];
        ushort4 u; u.x = f2bf(f.x); u.y = f2bf(f.y); u.z = f2bf(f.z); u.w = f2bf(f.w);
        ((ushort4*)ipw_bf)[i] = u;
        return;
    }
    int j = i - 40960;
    if (j < 16896) {
        int r = j / 66, c = j - r * 66;
        featwT[(size_t)c * 256 + r] = feat_w[j];
        return;
    }
    j -= 16896;
    if (j < 131072) {
        int r = j >> 9, c = j & 511;
        h1wT[(size_t)c * 256 + r] = h1_w[j];
        return;
    }
    j -= 131072;
    if (j < 32768) {
        int r = j >> 8, c = j & 255;
        h2wT[(size_t)c * 128 + r] = h2_w[j];
    }
}

// Whole head, 16 blocks (one per batch row) x 256 thr; weights pre-transposed.
__global__ __launch_bounds__(256) void head_kernel(
    const float* __restrict__ x32, const float* __restrict__ features,
    const float* __restrict__ feat_wT, const float* __restrict__ feat_b,
    const float* __restrict__ feat_ln_g, const float* __restrict__ feat_ln_b,
    const float* __restrict__ h1_wT, const float* __restrict__ h1_b,
    const float* __restrict__ h_ln_g, const float* __restrict__ h_ln_b,
    const float* __restrict__ h2_wT, const float* __restrict__ h2_b,
    const float* __restrict__ h3_w, const float* __restrict__ h3_b,
    float* __restrict__ outp)
{
    __shared__ float xcat[512];
    __shared__ float h1s[256];
    __shared__ float red[8];
    __shared__ float r2[128];
    const int r = blockIdx.x, t = threadIdx.x;
    const int wid = t >> 6, lane = t & 63;

    xcat[t] = x32[((size_t)r * S_LEN + S_LEN / 2) * DMODEL + t];

    const float* frow = features + (size_t)r * 66;
    float s = feat_b[t];
    for (int k = 0; k < 66; ++k) s = fmaf(frow[k], feat_wT[k * 256 + t], s);
    {
        float a = s, a2 = s * s;
        #pragma unroll
        for (int off = 32; off; off >>= 1) { a += __shfl_xor(a, off, 64); a2 += __shfl_xor(a2, off, 64); }
        if (lane == 0) { red[wid] = a; red[wid + 4] = a2; }
        __syncthreads();
        float ts = red[0] + red[1] + red[2] + red[3];
        float ts2 = red[4] + red[5] + red[6] + red[7];
        float m = ts * (1.0f / 256.0f);
        float var = ts2 * (1.0f / 256.0f) - m * m;
        float rstd = rsqrtf(var + 1e-5f);
        float v = (s - m) * rstd * feat_ln_g[t] + feat_ln_b[t];
        xcat[256 + t] = gelu_f(v);
        __syncthreads();
    }

    s = h1_b[t];
    #pragma unroll 8
    for (int k = 0; k < 512; ++k) s = fmaf(xcat[k], h1_wT[k * 256 + t], s);
    {
        float a = s, a2 = s * s;
        #pragma unroll
        for (int off = 32; off; off >>= 1) { a += __shfl_xor(a, off, 64); a2 += __shfl_xor(a2, off, 64); }
        if (lane == 0) { red[wid] = a; red[wid + 4] = a2; }
        __syncthreads();
        float ts = red[0] + red[1] + red[2] + red[3];
        float ts2 = red[4] + red[5] + red[6] + red[7];
        float m = ts * (1.0f / 256.0f);
        float var = ts2 * (1.0f / 256.0f) - m * m;
        float rstd = rsqrtf(var + 1e-5f);
        float v = (s - m) * rstd * h_ln_g[t] + h_ln_b[t];
        h1s[t] = gelu_f(v);
        __syncthreads();
    }

    if (t < 128) {
        float v = h2_b[t];
        #pragma unroll 8
        for (int k = 0; k < 256; ++k) v = fmaf(h1s[k], h2_wT[k * 128 + t], v);
        r2[t] = gelu_f(v) * h3_w[t];
    }
    __syncthreads();
    if (t < 64) {
        float p = r2[t] + r2[t + 64];
        #pragma unroll
        for (int off = 32; off; off >>= 1) p += __shfl_xor(p, off, 64);
        if (t == 0) outp[r] = p + h3_b[0];
    }
}

__global__ __launch_bounds__(256) void cvt_kernel(
    const float4* __restrict__ src, ushort4* __restrict__ dst, int n4)
{
    int i = blockIdx.x * 256 + threadIdx.x;
    if (i < n4) {
        float4 f = src[i];
        ushort4 u; u.x = f2bf(f.x); u.y = f2bf(f.y); u.z = f2bf(f.z); u.w = f2bf(f.w);
        dst[i] = u;
    }
}

__global__ __launch_bounds__(256) void qkvbias_kernel(
    const float* __restrict__ aib, const float* __restrict__ aiw,
    const float* __restrict__ se, float* __restrict__ eb)
{
    int i = blockIdx.x * 256 + threadIdx.x;   // < 12288
    int r = i % 3072, si = r / 768;
    const float* w = aiw + (size_t)i * 256;
    const float* s = se + si * 256;
    float acc = aib[i];
    for (int k = 0; k < 256; ++k) acc = fmaf(s[k], w[k], acc);
    eb[i] = acc;
}

__global__ __launch_bounds__(256) void fusbias_kernel(
    const float* __restrict__ fus_b, const float* __restrict__ fus_w,
    const float* __restrict__ aob, float* __restrict__ fb)
{
    int l = blockIdx.x, n = threadIdx.x;
    const float* w = fus_w + ((size_t)l * 256 + n) * 1024;
    const float* o = aob + (size_t)l * 1024;
    float acc = fus_b[l * 256 + n];
    for (int j = 0; j < 1024; ++j) acc = fmaf(o[j], w[j], acc);
    fb[l * 256 + n] = acc;
}

static inline void mgemm(hipStream_t s, const ushortT* A, int lda, const ushortT* W, int ldw,
                         const float* bias, const float* betaC, float* o32, ushortT* o16,
                         int ldc, int M, int N, int K, int flags)
{
    if (N >= 3072) {
        dim3 g(M / 128, N / 128);
        hipLaunchKernelGGL((mfma_gemm<128, 128>), g, dim3(256), 0, s,
                           A, lda, W, ldw, bias, betaC, o32, o16, ldc, K, flags);
    } else if (N >= 1024) {
        dim3 g(M / 64, N / 128);
        hipLaunchKernelGGL((mfma_gemm<64, 128>), g, dim3(256), 0, s,
                           A, lda, W, ldw, bias, betaC, o32, o16, ldc, K, flags);
    } else {
        dim3 g(M / 64, N / 64);
        hipLaunchKernelGGL((mfma_gemm<64, 64>), g, dim3(256), 0, s,
                           A, lda, W, ldw, bias, betaC, o32, o16, ldc, K, flags);
    }
}

static inline void cvt(hipStream_t s, const float* src, ushortT* dst, size_t n)
{
    int n4 = (int)(n / 4);
    hipLaunchKernelGGL(cvt_kernel, dim3((n4 + 255) / 256), dim3(256), 0, s,
                       (const float4*)src, (ushort4*)dst, n4);
}

extern "C" void kernel_launch(void* const* d_in, const int* in_sizes, int n_in,
                              void* d_out, int out_size, void* d_ws, size_t ws_size,
                              hipStream_t stream)
{
    const float* emb        = (const float*)d_in[0];
    const float* features   = (const float*)d_in[1];
    const float* ip_w       = (const float*)d_in[2];
    const float* ip_b       = (const float*)d_in[3];
    const float* scale_emb  = (const float*)d_in[4];
    const float* attn_in_w  = (const float*)d_in[5];
    const float* attn_in_b  = (const float*)d_in[6];
    const float* attn_out_w = (const float*)d_in[7];
    const float* attn_out_b = (const float*)d_in[8];
    const float* fus_w      = (const float*)d_in[9];
    const float* fus_b      = (const float*)d_in[10];
    const float* ffn_w1     = (const float*)d_in[11];
    const float* ffn_b1     = (const float*)d_in[12];
    const float* ffn_w2     = (const float*)d_in[13];
    const float* ffn_b2     = (const float*)d_in[14];
    const float* n1_g       = (const float*)d_in[15];
    const float* n1_b       = (const float*)d_in[16];
    const float* n2_g       = (const float*)d_in[17];
    const float* n2_b       = (const float*)d_in[18];
    const float* feat_w     = (const float*)d_in[19];
    const float* feat_b     = (const float*)d_in[20];
    const float* feat_ln_g  = (const float*)d_in[21];
    const float* feat_ln_b  = (const float*)d_in[22];
    const float* h1_w       = (const float*)d_in[23];
    const float* h1_b       = (const float*)d_in[24];
    const float* h_ln_g     = (const float*)d_in[25];
    const float* h_ln_b     = (const float*)d_in[26];
    const float* h2_w       = (const float*)d_in[27];
    const float* h2_b       = (const float*)d_in[28];
    const float* h3_w       = (const float*)d_in[29];
    const float* h3_b       = (const float*)d_in[30];
    float* outp = (float*)d_out;

    const int Btok = 16 * S_LEN;   // 8192

    // ---- workspace carve-up ----
    char* p = (char*)d_ws;
    float* x32     = (float*)p;              p += (size_t)Btok * DMODEL * 4;
    float* effqkvb = (float*)p;              p += 12288 * 4;
    float* fusbias = (float*)p;              p += 1024 * 4;
    float* featwT  = (float*)p;              p += 66 * 256 * 4;
    float* h1wT    = (float*)p;              p += 512 * 256 * 4;
    float* h2wT    = (float*)p;              p += 256 * 128 * 4;
    ushortT* xbf   = (ushortT*)p;            p += (size_t)Btok * DMODEL * 2;
    ushortT* qkv4  = (ushortT*)p;            p += (size_t)Btok * 3072 * 2;   // all 4 scales
    ushortT* ocat  = (ushortT*)p;            p += (size_t)Btok * 1024 * 2;
    ushortT* ipw_bf  = (ushortT*)p;          p += (size_t)DMODEL * 640 * 2;
    ushortT* aiw_bf  = (ushortT*)p;          p += (size_t)16 * 768 * 256 * 2;
    ushortT* wcat_bf = (ushortT*)p;          p += (size_t)4 * 256 * 1024 * 2;
    ushortT* f1_bf   = (ushortT*)p;          p += (size_t)4 * 1024 * 256 * 2;
    ushortT* f2_bf   = (ushortT*)p;          p += (size_t)4 * 256 * 1024 * 2;
    ushortT* embbf = qkv4;                   // alias: emb_bf dead before layer-0 qkv
    ushortT* midbf = ocat;                   // alias: ffn mid after ocat consumed

    // ---- precompute ----
    cvt(stream, emb, embbf, (size_t)Btok * 640);
    cvt(stream, attn_in_w, aiw_bf, (size_t)16 * 768 * 256);
    cvt(stream, ffn_w1, f1_bf, (size_t)4 * 1024 * 256);
    cvt(stream, ffn_w2, f2_bf, (size_t)4 * 256 * 1024);
    hipLaunchKernelGGL(prep_misc, dim3(866), dim3(256), 0, stream,
                       ip_w, ipw_bf, feat_w, featwT, h1_w, h1wT, h2_w, h2wT);
    hipLaunchKernelGGL(wc_mfma, dim3(2, 2, 16), dim3(256), 0, stream,
                       fus_w, attn_out_w, wcat_bf);
    hipLaunchKernelGGL(qkvbias_kernel, dim3(48), dim3(256), 0, stream,
                       attn_in_b, attn_in_w, scale_emb, effqkvb);
    hipLaunchKernelGGL(fusbias_kernel, dim3(4), dim3(256), 0, stream,
                       fus_b, fus_w, attn_out_b, fusbias);

    // ---- x = emb @ ip_w^T + ip_b + PE ----
    mgemm(stream, embbf, 640, ipw_bf, 640, ip_b, nullptr, x32, xbf,
          DMODEL, Btok, DMODEL, 640, F_PE);

    for (int l = 0; l < NLAYER; ++l) {
        // qkv for ALL 4 scales: N=3072, one launch
        mgemm(stream, xbf, DMODEL, aiw_bf + (size_t)l * 3072 * 256, DMODEL,
              effqkvb + (size_t)l * 3072, nullptr, nullptr, qkv4,
              3072, Btok, 3072, DMODEL, 0);
        hipLaunchKernelGGL(attn_mfma, dim3(4096), dim3(256), 0, stream, qkv4, ocat);
        // x = LN(x + ocat @ Wcat[l]^T + fusbias[l])   -- fused GEMM+LN, in-place x
        hipLaunchKernelGGL(gemm_ln, dim3(Btok / 16), dim3(256), 0, stream,
                           ocat, wcat_bf + (size_t)l * 256 * 1024,
                           fusbias + l * DMODEL, x32,
                           n1_g + l * DMODEL, n1_b + l * DMODEL, x32, xbf);
        // mid = gelu(x @ ffn1^T + b1)
        mgemm(stream, xbf, DMODEL, f1_bf + (size_t)l * 1024 * 256, DMODEL,
              ffn_b1 + (size_t)l * 1024, nullptr, nullptr, midbf,
              1024, Btok, 1024, DMODEL, F_GELU);
        // x = LN(x + mid @ ffn2^T + b2)   -- fused GEMM+LN, in-place x
        hipLaunchKernelGGL(gemm_ln, dim3(Btok / 16), dim3(256), 0, stream,
                           midbf, f2_bf + (size_t)l * 256 * 1024,
                           ffn_b2 + (size_t)l * DMODEL, x32,
                           n2_g + l * DMODEL, n2_b + l * DMODEL, x32, xbf);
    }

    // ---- head ----
    hipLaunchKernelGGL(head_kernel, dim3(16), dim3(256), 0, stream,
                       x32, features, featwT, feat_b, feat_ln_g, feat_ln_b,
                       h1wT, h1_b, h_ln_g, h_ln_b, h2wT, h2_b, h3_w, h3_b, outp);
}

// Round 13
// 720.233 us; speedup vs baseline: 1.2403x; 1.1238x over previous
//
#include <hip/hip_runtime.h>
#include <math.h>

#define S_LEN 512
#define DMODEL 256
#define NHEAD 8
#define HDIM 32
#define NLAYER 4
#define NSCALE 4

typedef unsigned short ushortT;
typedef unsigned int uintT;
typedef short bf16x8 __attribute__((ext_vector_type(8)));
typedef float f32x4 __attribute__((ext_vector_type(4)));

enum { F_PE = 1, F_BETA = 2, F_GELU = 4 };

__device__ __forceinline__ float gelu_f(float x) {
    return 0.5f * x * (1.0f + erff(x * 0.70710678118654752440f));
}
__device__ __forceinline__ ushortT f2bf(float f) {
    union { float f; uintT i; } u; u.f = f;
    uintT r = u.i + 0x7FFF + ((u.i >> 16) & 1);   // RNE
    return (ushortT)(r >> 16);
}
__device__ __forceinline__ int swz(int r) { return (r & 3) ^ ((r >> 2) & 3); }

#define GLD16(g, l) \
    __builtin_amdgcn_global_load_lds((const __attribute__((address_space(1))) void*)(g), \
                                     (__attribute__((address_space(3))) void*)(l), 16, 0, 0)

// C[M,N] = op(A[M,K]bf16 @ W[N,K]bf16^T + bias) ; M%BM==0, N%BN==0, K%32==0
// (R8 version: BK=32, 16KB LDS — best measured occupancy/time)
template<int BM, int BN>
__global__ __launch_bounds__(256) void mfma_gemm(
    const ushortT* __restrict__ A, int lda,
    const ushortT* __restrict__ W, int ldw,
    const float* __restrict__ bias,
    const float* __restrict__ betaC,
    float* __restrict__ out32,
    ushortT* __restrict__ out16,
    int ldc, int K, int flags)
{
    constexpr int MI = BM / 32;
    constexpr int NI = BN / 32;
    __shared__ __align__(16) ushortT As[BM * 32];
    __shared__ __align__(16) ushortT Bs[BN * 32];
    const int tid = threadIdx.x;
    const int wave = tid >> 6, lane = tid & 63;
    const int l15 = lane & 15, qd = lane >> 4;
    const int m0 = blockIdx.x * BM, n0 = blockIdx.y * BN;
    const int wm = (wave >> 1) * (BM / 2), wn = (wave & 1) * (BN / 2);

    f32x4 acc[MI][NI];
    #pragma unroll
    for (int i = 0; i < MI; ++i)
        #pragma unroll
        for (int j = 0; j < NI; ++j) acc[i][j] = (f32x4){0.f, 0.f, 0.f, 0.f};

    for (int k0 = 0; k0 < K; k0 += 32) {
        #pragma unroll
        for (int it = 0; it < BM / 64; ++it) {
            int c = it * 256 + tid;
            int m = c >> 2, s = c & 3;
            int kc = s ^ swz(m);
            GLD16(A + (size_t)(m0 + m) * lda + k0 + kc * 8,
                  (ushortT*)As + (size_t)(it * 256 + wave * 64) * 8);
        }
        #pragma unroll
        for (int it = 0; it < BN / 64; ++it) {
            int c = it * 256 + tid;
            int n = c >> 2, s = c & 3;
            int kc = s ^ swz(n);
            GLD16(W + (size_t)(n0 + n) * ldw + k0 + kc * 8,
                  (ushortT*)Bs + (size_t)(it * 256 + wave * 64) * 8);
        }
        __syncthreads();
        bf16x8 af[MI], bfr[NI];
        #pragma unroll
        for (int mi = 0; mi < MI; ++mi) {
            int r = wm + mi * 16 + l15;
            af[mi] = *(const bf16x8*)(As + r * 32 + (qd ^ swz(r)) * 8);
        }
        #pragma unroll
        for (int ni = 0; ni < NI; ++ni) {
            int r = wn + ni * 16 + l15;
            bfr[ni] = *(const bf16x8*)(Bs + r * 32 + (qd ^ swz(r)) * 8);
        }
        #pragma unroll
        for (int mi = 0; mi < MI; ++mi)
            #pragma unroll
            for (int ni = 0; ni < NI; ++ni)
                acc[mi][ni] = __builtin_amdgcn_mfma_f32_16x16x32_bf16(
                    af[mi], bfr[ni], acc[mi][ni], 0, 0, 0);
        __syncthreads();
    }

    #pragma unroll
    for (int mi = 0; mi < MI; ++mi) {
        #pragma unroll
        for (int ni = 0; ni < NI; ++ni) {
            int col = n0 + wn + ni * 16 + l15;
            float bv = bias ? bias[col] : 0.f;
            #pragma unroll
            for (int r = 0; r < 4; ++r) {
                int grow = m0 + wm + mi * 16 + qd * 4 + r;
                float v = acc[mi][ni][r] + bv;
                if (flags & F_BETA) v += betaC[(size_t)grow * ldc + col];
                if (flags & F_PE) {
                    int pos = grow & (S_LEN - 1);
                    float div = expf((float)(col & ~1) * (-9.210340371976184f / 256.0f));
                    float ang = (float)pos * div;
                    v += (col & 1) ? cosf(ang) : sinf(ang);
                }
                if (flags & F_GELU) v = gelu_f(v);
                if (out32) out32[(size_t)grow * ldc + col] = v;
                if (out16) out16[(size_t)grow * ldc + col] = f2bf(v);
            }
        }
    }
}

// Full-row GEMM + fused LayerNorm. Tile 16 rows x 256 cols, K=1024, BK=128.
// Grid-limited to 2 blocks/CU, so the 68KB LDS is free; 8 barrier-drains (was 32).
//   pre[m,n] = A[m,:]@W[n,:]^T + bias[n] + betaC[m,n]
//   y = LN_row(pre) * g + be ;  writes o32 (fp32, may alias betaC) + o16 (bf16)
__global__ __launch_bounds__(256) void gemm_ln(
    const ushortT* __restrict__ A,          // (M,1024) bf16
    const ushortT* __restrict__ W,          // (256,1024) bf16
    const float* __restrict__ bias,
    const float* __restrict__ betaC,        // (M,256) fp32 residual
    const float* __restrict__ g, const float* __restrict__ be,
    float* __restrict__ o32, ushortT* __restrict__ o16)
{
    __shared__ __align__(16) ushortT As[16 * 128];    // 4 KB
    __shared__ __align__(16) ushortT Bs[256 * 128];   // 64 KB
    __shared__ float redS[64], redQ[64];
    const int tid = threadIdx.x;
    const int wave = tid >> 6, lane = tid & 63;
    const int l15 = lane & 15, qd = lane >> 4;
    const int m0 = blockIdx.x * 16;

    f32x4 acc[4];
    #pragma unroll
    for (int j = 0; j < 4; ++j) acc[j] = (f32x4){0.f, 0.f, 0.f, 0.f};

    for (int k0 = 0; k0 < 1024; k0 += 128) {
        // A: 16 rows x 16 chunks of 8; slot s of row m holds chunk s^m
        {
            int m = tid >> 4, s = tid & 15;
            int kc = s ^ m;
            GLD16(A + (size_t)(m0 + m) * 1024 + k0 + kc * 8,
                  (ushortT*)As + (size_t)(wave * 64) * 8);
        }
        // B: 256 rows x 16 chunks; slot s of row n holds chunk s^(n&15)
        #pragma unroll
        for (int it = 0; it < 16; ++it) {
            int c = it * 256 + tid;
            int n = c >> 4, s = c & 15;
            int kc = s ^ (n & 15);
            GLD16(W + (size_t)n * 1024 + k0 + kc * 8,
                  (ushortT*)Bs + (size_t)(it * 256 + wave * 64) * 8);
        }
        __syncthreads();
        #pragma unroll
        for (int kk = 0; kk < 4; ++kk) {
            int sl = (kk * 4 + qd) ^ l15;
            bf16x8 af = *(const bf16x8*)(As + (l15 * 16 + sl) * 8);
            #pragma unroll
            for (int ni = 0; ni < 4; ++ni) {
                int n = wave * 64 + ni * 16 + l15;
                bf16x8 bfr = *(const bf16x8*)(Bs + ((size_t)n * 16 + sl) * 8);
                acc[ni] = __builtin_amdgcn_mfma_f32_16x16x32_bf16(af, bfr, acc[ni], 0, 0, 0);
            }
        }
        __syncthreads();
    }

    // epilogue: bias + residual, then row LN
    float v[4][4];                             // [ni][rg]
    #pragma unroll
    for (int ni = 0; ni < 4; ++ni) {
        int col = wave * 64 + ni * 16 + l15;
        float bv = bias[col];
        #pragma unroll
        for (int rg = 0; rg < 4; ++rg) {
            int row = qd * 4 + rg;
            v[ni][rg] = acc[ni][rg] + bv + betaC[(size_t)(m0 + row) * 256 + col];
        }
    }
    float sr[4], sq[4];
    #pragma unroll
    for (int rg = 0; rg < 4; ++rg) {
        sr[rg] = v[0][rg] + v[1][rg] + v[2][rg] + v[3][rg];
        sq[rg] = v[0][rg] * v[0][rg] + v[1][rg] * v[1][rg]
               + v[2][rg] * v[2][rg] + v[3][rg] * v[3][rg];
    }
    #pragma unroll
    for (int m = 1; m < 16; m <<= 1) {
        #pragma unroll
        for (int rg = 0; rg < 4; ++rg) {
            sr[rg] += __shfl_xor(sr[rg], m, 64);
            sq[rg] += __shfl_xor(sq[rg], m, 64);
        }
    }
    if (l15 == 0) {
        #pragma unroll
        for (int rg = 0; rg < 4; ++rg) {
            redS[wave * 16 + qd * 4 + rg] = sr[rg];
            redQ[wave * 16 + qd * 4 + rg] = sq[rg];
        }
    }
    __syncthreads();
    float mean[4], rstd[4];
    #pragma unroll
    for (int rg = 0; rg < 4; ++rg) {
        int row = qd * 4 + rg;
        float ts = redS[row] + redS[16 + row] + redS[32 + row] + redS[48 + row];
        float tq = redQ[row] + redQ[16 + row] + redQ[32 + row] + redQ[48 + row];
        float m = ts * (1.0f / 256.0f);
        float var = tq * (1.0f / 256.0f) - m * m;
        mean[rg] = m;
        rstd[rg] = rsqrtf(var + 1e-5f);
    }
    #pragma unroll
    for (int ni = 0; ni < 4; ++ni) {
        int col = wave * 64 + ni * 16 + l15;
        float gv = g[col], bev = be[col];
        #pragma unroll
        for (int rg = 0; rg < 4; ++rg) {
            int row = qd * 4 + rg;
            float y = (v[ni][rg] - mean[rg]) * rstd[rg] * gv + bev;
            o32[(size_t)(m0 + row) * 256 + col] = y;
            o16[(size_t)(m0 + row) * 256 + col] = f2bf(y);
        }
    }
}

// Batched MFMA for Wcat: for each ls=(l,si):
//   Wcat[l][n][si*256+j] = sum_p fus_w[l][n][si*256+p] * ao_w[ls][p][j]
__global__ __launch_bounds__(256) void wc_mfma(
    const float* __restrict__ fus_w, const float* __restrict__ ao_w,
    ushortT* __restrict__ Wcat)
{
    __shared__ __align__(16) ushortT As[128 * 32];
    __shared__ __align__(16) ushortT Bs[128 * 32];
    const int z = blockIdx.z, l = z >> 2, si = z & 3;
    const int m0 = blockIdx.x * 128, n0 = blockIdx.y * 128;
    const int tid = threadIdx.x;
    const int wave = tid >> 6, lane = tid & 63;
    const int l15 = lane & 15, qd = lane >> 4;
    const int wm = (wave >> 1) * 64, wn = (wave & 1) * 64;
    const float* Abase = fus_w + ((size_t)(l * 256) + m0) * 1024 + si * 256;
    const float* Bbase = ao_w + (size_t)z * 65536;

    f32x4 acc[4][4];
    #pragma unroll
    for (int i = 0; i < 4; ++i)
        #pragma unroll
        for (int j = 0; j < 4; ++j) acc[i][j] = (f32x4){0.f, 0.f, 0.f, 0.f};

    const int am = tid >> 1, ah = tid & 1;
    const int bp = tid >> 3, bj = (tid & 7) * 16;

    for (int k0 = 0; k0 < 256; k0 += 32) {
        #pragma unroll
        for (int j = 0; j < 2; ++j) {
            const float* src = Abase + (size_t)am * 1024 + k0 + ah * 16 + j * 8;
            float4 f0 = *(const float4*)src;
            float4 f1 = *(const float4*)(src + 4);
            int sc = ah * 2 + j;
            ushortT* d = As + am * 32 + (sc ^ swz(am)) * 8;
            ushort4 u0; u0.x = f2bf(f0.x); u0.y = f2bf(f0.y); u0.z = f2bf(f0.z); u0.w = f2bf(f0.w);
            ushort4 u1; u1.x = f2bf(f1.x); u1.y = f2bf(f1.y); u1.z = f2bf(f1.z); u1.w = f2bf(f1.w);
            *(ushort4*)d = u0; *(ushort4*)(d + 4) = u1;
        }
        #pragma unroll
        for (int c = 0; c < 4; ++c) {
            float4 f = *(const float4*)(Bbase + (size_t)(k0 + bp) * 256 + n0 + bj + c * 4);
            float vv[4] = {f.x, f.y, f.z, f.w};
            #pragma unroll
            for (int e = 0; e < 4; ++e) {
                int r = bj + c * 4 + e;
                Bs[r * 32 + (((bp >> 3) ^ swz(r)) * 8) + (bp & 7)] = f2bf(vv[e]);
            }
        }
        __syncthreads();
        bf16x8 af[4], bfr[4];
        #pragma unroll
        for (int mi = 0; mi < 4; ++mi) {
            int r = wm + mi * 16 + l15;
            af[mi] = *(const bf16x8*)(As + r * 32 + (qd ^ swz(r)) * 8);
        }
        #pragma unroll
        for (int ni = 0; ni < 4; ++ni) {
            int r = wn + ni * 16 + l15;
            bfr[ni] = *(const bf16x8*)(Bs + r * 32 + (qd ^ swz(r)) * 8);
        }
        #pragma unroll
        for (int mi = 0; mi < 4; ++mi)
            #pragma unroll
            for (int ni = 0; ni < 4; ++ni)
                acc[mi][ni] = __builtin_amdgcn_mfma_f32_16x16x32_bf16(
                    af[mi], bfr[ni], acc[mi][ni], 0, 0, 0);
        __syncthreads();
    }

    #pragma unroll
    for (int mi = 0; mi < 4; ++mi) {
        #pragma unroll
        for (int ni = 0; ni < 4; ++ni) {
            int col = n0 + wn + ni * 16 + l15;
            #pragma unroll
            for (int r = 0; r < 4; ++r) {
                int row = m0 + wm + mi * 16 + qd * 4 + r;
                Wcat[((size_t)(l * 256) + row) * 1024 + si * 256 + col] =
                    f2bf(acc[mi][ni][r]);
            }
        }
    }
}

// MFMA banded attention, ALL 4 scales per launch.
// qkv: (B*S, 3072) = 4 scales x (q|k|v * 256). Block = (slot, qblk, h, b).
__global__ __launch_bounds__(256) void attn_mfma(
    const ushortT* __restrict__ qkv, ushortT* __restrict__ ocat)
{
    __shared__ __align__(16) ushortT Vt[32 * 216];     // [d][key_local], stride 216
    __shared__ __align__(16) ushortT Pl[4][16 * 168];  // per-wave P, stride 168
    const int bid = blockIdx.x;
    const int sp   = bid & 3;            // scale slot
    const int qblk = (bid >> 2) & 7;
    const int h    = (bid >> 5) & 7;
    const int b    = (bid >> 8) & 15;
    const int RAD[4] = {5, 10, 20, 50};
    const int r = RAD[sp];
    const int lcol = sp * 768;
    const int tid = threadIdx.x;

    const int q0blk = qblk * 64;
    const int t0 = max(0, q0blk - r) >> 4;
    const int t1 = min(S_LEN - 1, q0blk + 63 + r) >> 4;
    const int nstage = (t1 - t0 + 2) * 16;   // +1 zero pad tile
    const int kmax = min(S_LEN - 1, t1 * 16 + 15);

    const ushortT* bbase = qkv + (size_t)(b * S_LEN) * 3072 + lcol;

    for (int idx = tid; idx < nstage * 4; idx += 256) {
        int row = idx >> 2, dch = idx & 3;
        int key = t0 * 16 + row;
        uint4 u = make_uint4(0, 0, 0, 0);
        if (key <= kmax)
            u = *(const uint4*)(bbase + (size_t)key * 3072 + 512 + h * HDIM + dch * 8);
        ushortT* dst = &Vt[(dch * 8) * 216 + row];
        uintT w[4] = {u.x, u.y, u.z, u.w};
        #pragma unroll
        for (int t = 0; t < 4; ++t) {
            dst[(2 * t) * 216]     = (ushortT)(w[t] & 0xffff);
            dst[(2 * t + 1) * 216] = (ushortT)(w[t] >> 16);
        }
    }

    const int wid = tid >> 6, lane = tid & 63;
    const int quad = lane >> 4, l15 = lane & 15;
    ushortT* Pw = Pl[wid];

    {
        uint4 z = make_uint4(0, 0, 0, 0);
        #pragma unroll
        for (int i = 0; i < 6; ++i) {
            int c = lane + i * 64;
            if (c < 336) ((uint4*)Pw)[c] = z;
        }
    }
    __syncthreads();

    const int q0w = q0blk + wid * 16;
    bf16x8 qf = *(const bf16x8*)(bbase + (size_t)(q0w + l15) * 3072 + h * HDIM + quad * 8);

    const int kt0 = max(0, q0w - r) >> 4;
    const int kt1 = min(S_LEN - 1, q0w + 15 + r) >> 4;
    const int nt = kt1 - kt0 + 1;

    f32x4 rs4 = (f32x4){0.f, 0.f, 0.f, 0.f};
    const unsigned span = (unsigned)(2 * r);

    for (int kt = kt0; kt <= kt1; ++kt) {
        int key = kt * 16 + l15;
        bf16x8 kf = *(const bf16x8*)(bbase + (size_t)key * 3072 + 256 + h * HDIM + quad * 8);
        f32x4 s4 = __builtin_amdgcn_mfma_f32_16x16x32_bf16(
            qf, kf, (f32x4){0.f, 0.f, 0.f, 0.f}, 0, 0, 0);
        #pragma unroll
        for (int rg = 0; rg < 4; ++rg) {
            int q = q0w + quad * 4 + rg;
            unsigned dd = (unsigned)(key - q + r);
            float p = (dd <= span)
                      ? __expf(fminf(s4[rg] * 0.17677669529663688f, 80.f)) : 0.f;
            rs4[rg] += p;
            Pw[(quad * 4 + rg) * 168 + (kt - kt0) * 16 + l15] = f2bf(p);
        }
    }

    #pragma unroll
    for (int m = 1; m < 16; m <<= 1) {
        #pragma unroll
        for (int rg = 0; rg < 4; ++rg) rs4[rg] += __shfl_xor(rs4[rg], m, 64);
    }

    f32x4 o0 = (f32x4){0.f, 0.f, 0.f, 0.f};
    f32x4 o1 = (f32x4){0.f, 0.f, 0.f, 0.f};
    const int basek = (kt0 - t0) * 16;
    const int nch = (nt + 1) >> 1;
    for (int c = 0; c < nch; ++c) {
        bf16x8 pa = *(const bf16x8*)(Pw + l15 * 168 + c * 32 + quad * 8);
        bf16x8 v0 = *(const bf16x8*)(&Vt[l15 * 216 + basek + c * 32 + quad * 8]);
        bf16x8 v1 = *(const bf16x8*)(&Vt[(l15 + 16) * 216 + basek + c * 32 + quad * 8]);
        o0 = __builtin_amdgcn_mfma_f32_16x16x32_bf16(pa, v0, o0, 0, 0, 0);
        o1 = __builtin_amdgcn_mfma_f32_16x16x32_bf16(pa, v1, o1, 0, 0, 0);
    }

    #pragma unroll
    for (int rg = 0; rg < 4; ++rg) {
        float inv = 1.0f / rs4[rg];
        int q = q0w + quad * 4 + rg;
        ushortT* op = ocat + ((size_t)(b * S_LEN) + q) * 1024 + sp * DMODEL + h * HDIM;
        op[l15]      = f2bf(o0[rg] * inv);
        op[16 + l15] = f2bf(o1[rg] * inv);
    }
}

// one merged precompute: all fp32->bf16 cvts + weight transposes, range-switched
__global__ __launch_bounds__(256) void prep_all(
    const float* __restrict__ emb, ushortT* __restrict__ embd,
    const float* __restrict__ aiw, ushortT* __restrict__ aiwd,
    const float* __restrict__ f1s, ushortT* __restrict__ f1d,
    const float* __restrict__ f2s, ushortT* __restrict__ f2d,
    const float* __restrict__ ip_w, ushortT* __restrict__ ipwd,
    const float* __restrict__ feat_w, float* __restrict__ featwT,
    const float* __restrict__ h1_w, float* __restrict__ h1wT,
    const float* __restrict__ h2_w, float* __restrict__ h2wT)
{
    int i = blockIdx.x * 256 + threadIdx.x;
    if (i < 1310720) {            // emb: 5.24M elems as float4
        float4 f = ((const float4*)emb)[i];
        ushort4 u; u.x = f2bf(f.x); u.y = f2bf(f.y); u.z = f2bf(f.z); u.w = f2bf(f.w);
        ((ushort4*)embd)[i] = u; return;
    }
    i -= 1310720;
    if (i < 786432) {             // attn_in_w
        float4 f = ((const float4*)aiw)[i];
        ushort4 u; u.x = f2bf(f.x); u.y = f2bf(f.y); u.z = f2bf(f.z); u.w = f2bf(f.w);
        ((ushort4*)aiwd)[i] = u; return;
    }
    i -= 786432;
    if (i < 262144) {             // ffn_w1
        float4 f = ((const float4*)f1s)[i];
        ushort4 u; u.x = f2bf(f.x); u.y = f2bf(f.y); u.z = f2bf(f.z); u.w = f2bf(f.w);
        ((ushort4*)f1d)[i] = u; return;
    }
    i -= 262144;
    if (i < 262144) {             // ffn_w2
        float4 f = ((const float4*)f2s)[i];
        ushort4 u; u.x = f2bf(f.x); u.y = f2bf(f.y); u.z = f2bf(f.z); u.w = f2bf(f.w);
        ((ushort4*)f2d)[i] = u; return;
    }
    i -= 262144;
    if (i < 40960) {              // ip_w
        float4 f = ((const float4*)ip_w)[i];
        ushort4 u; u.x = f2bf(f.x); u.y = f2bf(f.y); u.z = f2bf(f.z); u.w = f2bf(f.w);
        ((ushort4*)ipwd)[i] = u; return;
    }
    i -= 40960;
    if (i < 16896) {              // feat_w 256x66 -> T
        int r = i / 66, c = i - r * 66;
        featwT[(size_t)c * 256 + r] = feat_w[i]; return;
    }
    i -= 16896;
    if (i < 131072) {             // h1_w 256x512 -> T
        int r = i >> 9, c = i & 511;
        h1wT[(size_t)c * 256 + r] = h1_w[i]; return;
    }
    i -= 131072;
    if (i < 32768) {              // h2_w 128x256 -> T
        int r = i >> 8, c = i & 255;
        h2wT[(size_t)c * 128 + r] = h2_w[i];
    }
}

// wave-per-output GEMVs (coalesced lane reads + shuffle reduce)
__global__ __launch_bounds__(256) void qkvbias_wave(
    const float* __restrict__ aib, const float* __restrict__ aiw,
    const float* __restrict__ se, float* __restrict__ eb)
{
    int i = blockIdx.x * 4 + (threadIdx.x >> 6);   // output row 0..12287
    int lane = threadIdx.x & 63;
    int si = (i % 3072) / 768;
    const float* w = aiw + (size_t)i * 256;
    const float* s = se + si * 256;
    float acc = 0.f;
    #pragma unroll
    for (int t = 0; t < 4; ++t) acc = fmaf(s[lane + 64 * t], w[lane + 64 * t], acc);
    #pragma unroll
    for (int off = 32; off; off >>= 1) acc += __shfl_xor(acc, off, 64);
    if (lane == 0) eb[i] = acc + aib[i];
}

__global__ __launch_bounds__(64) void fusbias_wave(
    const float* __restrict__ fus_b, const float* __restrict__ fus_w,
    const float* __restrict__ aob, float* __restrict__ fb)
{
    int idx = blockIdx.x;                          // l*256+n, 0..1023
    int l = idx >> 8;
    int lane = threadIdx.x;
    const float* w = fus_w + (size_t)idx * 1024;
    const float* o = aob + (size_t)l * 1024;
    float acc = 0.f;
    #pragma unroll
    for (int t = 0; t < 16; ++t) acc = fmaf(o[lane + 64 * t], w[lane + 64 * t], acc);
    #pragma unroll
    for (int off = 32; off; off >>= 1) acc += __shfl_xor(acc, off, 64);
    if (lane == 0) fb[idx] = acc + fus_b[idx];
}

// Whole head, 16 blocks (one per batch row) x 256 thr; weights pre-transposed.
__global__ __launch_bounds__(256) void head_kernel(
    const float* __restrict__ x32, const float* __restrict__ features,
    const float* __restrict__ feat_wT, const float* __restrict__ feat_b,
    const float* __restrict__ feat_ln_g, const float* __restrict__ feat_ln_b,
    const float* __restrict__ h1_wT, const float* __restrict__ h1_b,
    const float* __restrict__ h_ln_g, const float* __restrict__ h_ln_b,
    const float* __restrict__ h2_wT, const float* __restrict__ h2_b,
    const float* __restrict__ h3_w, const float* __restrict__ h3_b,
    float* __restrict__ outp)
{
    __shared__ float xcat[512];
    __shared__ float h1s[256];
    __shared__ float red[8];
    __shared__ float r2[128];
    const int r = blockIdx.x, t = threadIdx.x;
    const int wid = t >> 6, lane = t & 63;

    xcat[t] = x32[((size_t)r * S_LEN + S_LEN / 2) * DMODEL + t];

    const float* frow = features + (size_t)r * 66;
    float s = feat_b[t];
    for (int k = 0; k < 66; ++k) s = fmaf(frow[k], feat_wT[k * 256 + t], s);
    {
        float a = s, a2 = s * s;
        #pragma unroll
        for (int off = 32; off; off >>= 1) { a += __shfl_xor(a, off, 64); a2 += __shfl_xor(a2, off, 64); }
        if (lane == 0) { red[wid] = a; red[wid + 4] = a2; }
        __syncthreads();
        float ts = red[0] + red[1] + red[2] + red[3];
        float ts2 = red[4] + red[5] + red[6] + red[7];
        float m = ts * (1.0f / 256.0f);
        float var = ts2 * (1.0f / 256.0f) - m * m;
        float rstd = rsqrtf(var + 1e-5f);
        float v = (s - m) * rstd * feat_ln_g[t] + feat_ln_b[t];
        xcat[256 + t] = gelu_f(v);
        __syncthreads();
    }

    s = h1_b[t];
    #pragma unroll 8
    for (int k = 0; k < 512; ++k) s = fmaf(xcat[k], h1_wT[k * 256 + t], s);
    {
        float a = s, a2 = s * s;
        #pragma unroll
        for (int off = 32; off; off >>= 1) { a += __shfl_xor(a, off, 64); a2 += __shfl_xor(a2, off, 64); }
        if (lane == 0) { red[wid] = a; red[wid + 4] = a2; }
        __syncthreads();
        float ts = red[0] + red[1] + red[2] + red[3];
        float ts2 = red[4] + red[5] + red[6] + red[7];
        float m = ts * (1.0f / 256.0f);
        float var = ts2 * (1.0f / 256.0f) - m * m;
        float rstd = rsqrtf(var + 1e-5f);
        float v = (s - m) * rstd * h_ln_g[t] + h_ln_b[t];
        h1s[t] = gelu_f(v);
        __syncthreads();
    }

    if (t < 128) {
        float v = h2_b[t];
        #pragma unroll 8
        for (int k = 0; k < 256; ++k) v = fmaf(h1s[k], h2_wT[k * 128 + t], v);
        r2[t] = gelu_f(v) * h3_w[t];
    }
    __syncthreads();
    if (t < 64) {
        float p = r2[t] + r2[t + 64];
        #pragma unroll
        for (int off = 32; off; off >>= 1) p += __shfl_xor(p, off, 64);
        if (t == 0) outp[r] = p + h3_b[0];
    }
}

static inline void mgemm(hipStream_t s, const ushortT* A, int lda, const ushortT* W, int ldw,
                         const float* bias, const float* betaC, float* o32, ushortT* o16,
                         int ldc, int M, int N, int K, int flags)
{
    if (N >= 3072) {
        dim3 g(M / 128, N / 128);
        hipLaunchKernelGGL((mfma_gemm<128, 128>), g, dim3(256), 0, s,
                           A, lda, W, ldw, bias, betaC, o32, o16, ldc, K, flags);
    } else if (N >= 1024) {
        dim3 g(M / 64, N / 128);
        hipLaunchKernelGGL((mfma_gemm<64, 128>), g, dim3(256), 0, s,
                           A, lda, W, ldw, bias, betaC, o32, o16, ldc, K, flags);
    } else {
        dim3 g(M / 64, N / 64);
        hipLaunchKernelGGL((mfma_gemm<64, 64>), g, dim3(256), 0, s,
                           A, lda, W, ldw, bias, betaC, o32, o16, ldc, K, flags);
    }
}

extern "C" void kernel_launch(void* const* d_in, const int* in_sizes, int n_in,
                              void* d_out, int out_size, void* d_ws, size_t ws_size,
                              hipStream_t stream)
{
    const float* emb        = (const float*)d_in[0];
    const float* features   = (const float*)d_in[1];
    const float* ip_w       = (const float*)d_in[2];
    const float* ip_b       = (const float*)d_in[3];
    const float* scale_emb  = (const float*)d_in[4];
    const float* attn_in_w  = (const float*)d_in[5];
    const float* attn_in_b  = (const float*)d_in[6];
    const float* attn_out_w = (const float*)d_in[7];
    const float* attn_out_b = (const float*)d_in[8];
    const float* fus_w      = (const float*)d_in[9];
    const float* fus_b      = (const float*)d_in[10];
    const float* ffn_w1     = (const float*)d_in[11];
    const float* ffn_b1     = (const float*)d_in[12];
    const float* ffn_w2     = (const float*)d_in[13];
    const float* ffn_b2     = (const float*)d_in[14];
    const float* n1_g       = (const float*)d_in[15];
    const float* n1_b       = (const float*)d_in[16];
    const float* n2_g       = (const float*)d_in[17];
    const float* n2_b       = (const float*)d_in[18];
    const float* feat_w     = (const float*)d_in[19];
    const float* feat_b     = (const float*)d_in[20];
    const float* feat_ln_g  = (const float*)d_in[21];
    const float* feat_ln_b  = (const float*)d_in[22];
    const float* h1_w       = (const float*)d_in[23];
    const float* h1_b       = (const float*)d_in[24];
    const float* h_ln_g     = (const float*)d_in[25];
    const float* h_ln_b     = (const float*)d_in[26];
    const float* h2_w       = (const float*)d_in[27];
    const float* h2_b       = (const float*)d_in[28];
    const float* h3_w       = (const float*)d_in[29];
    const float* h3_b       = (const float*)d_in[30];
    float* outp = (float*)d_out;

    const int Btok = 16 * S_LEN;   // 8192

    // ---- workspace carve-up ----
    char* p = (char*)d_ws;
    float* x32     = (float*)p;              p += (size_t)Btok * DMODEL * 4;
    float* effqkvb = (float*)p;              p += 12288 * 4;
    float* fusbias = (float*)p;              p += 1024 * 4;
    float* featwT  = (float*)p;              p += 66 * 256 * 4;
    float* h1wT    = (float*)p;              p += 512 * 256 * 4;
    float* h2wT    = (float*)p;              p += 256 * 128 * 4;
    ushortT* xbf   = (ushortT*)p;            p += (size_t)Btok * DMODEL * 2;
    ushortT* qkv4  = (ushortT*)p;            p += (size_t)Btok * 3072 * 2;   // all 4 scales
    ushortT* ocat  = (ushortT*)p;            p += (size_t)Btok * 1024 * 2;
    ushortT* ipw_bf  = (ushortT*)p;          p += (size_t)DMODEL * 640 * 2;
    ushortT* aiw_bf  = (ushortT*)p;          p += (size_t)16 * 768 * 256 * 2;
    ushortT* wcat_bf = (ushortT*)p;          p += (size_t)4 * 256 * 1024 * 2;
    ushortT* f1_bf   = (ushortT*)p;          p += (size_t)4 * 1024 * 256 * 2;
    ushortT* f2_bf   = (ushortT*)p;          p += (size_t)4 * 256 * 1024 * 2;
    ushortT* embbf = qkv4;                   // alias: emb_bf dead before layer-0 qkv
    ushortT* midbf = ocat;                   // alias: ffn mid after ocat consumed

    // ---- precompute: 4 launches ----
    hipLaunchKernelGGL(prep_all, dim3(11106), dim3(256), 0, stream,
                       emb, embbf, attn_in_w, aiw_bf, ffn_w1, f1_bf, ffn_w2, f2_bf,
                       ip_w, ipw_bf, feat_w, featwT, h1_w, h1wT, h2_w, h2wT);
    hipLaunchKernelGGL(wc_mfma, dim3(2, 2, 16), dim3(256), 0, stream,
                       fus_w, attn_out_w, wcat_bf);
    hipLaunchKernelGGL(qkvbias_wave, dim3(3072), dim3(256), 0, stream,
                       attn_in_b, attn_in_w, scale_emb, effqkvb);
    hipLaunchKernelGGL(fusbias_wave, dim3(1024), dim3(64), 0, stream,
                       fus_b, fus_w, attn_out_b, fusbias);

    // ---- x = emb @ ip_w^T + ip_b + PE ----
    mgemm(stream, embbf, 640, ipw_bf, 640, ip_b, nullptr, x32, xbf,
          DMODEL, Btok, DMODEL, 640, F_PE);

    for (int l = 0; l < NLAYER; ++l) {
        // qkv for ALL 4 scales: N=3072, one launch
        mgemm(stream, xbf, DMODEL, aiw_bf + (size_t)l * 3072 * 256, DMODEL,
              effqkvb + (size_t)l * 3072, nullptr, nullptr, qkv4,
              3072, Btok, 3072, DMODEL, 0);
        hipLaunchKernelGGL(attn_mfma, dim3(4096), dim3(256), 0, stream, qkv4, ocat);
        // x = LN(x + ocat @ Wcat[l]^T + fusbias[l])   -- fused GEMM+LN, in-place x
        hipLaunchKernelGGL(gemm_ln, dim3(Btok / 16), dim3(256), 0, stream,
                           ocat, wcat_bf + (size_t)l * 256 * 1024,
                           fusbias + l * DMODEL, x32,
                           n1_g + l * DMODEL, n1_b + l * DMODEL, x32, xbf);
        // mid = gelu(x @ ffn1^T + b1)
        mgemm(stream, xbf, DMODEL, f1_bf + (size_t)l * 1024 * 256, DMODEL,
              ffn_b1 + (size_t)l * 1024, nullptr, nullptr, midbf,
              1024, Btok, 1024, DMODEL, F_GELU);
        // x = LN(x + mid @ ffn2^T + b2)   -- fused GEMM+LN, in-place x
        hipLaunchKernelGGL(gemm_ln, dim3(Btok / 16), dim3(256), 0, stream,
                           midbf, f2_bf + (size_t)l * 256 * 1024,
                           ffn_b2 + (size_t)l * DMODEL, x32,
                           n2_g + l * DMODEL, n2_b + l * DMODEL, x32, xbf);
    }

    // ---- head ----
    hipLaunchKernelGGL(head_kernel, dim3(16), dim3(256), 0, stream,
                       x32, features, featwT, feat_b, feat_ln_g, feat_ln_b,
                       h1wT, h1_b, h_ln_g, h_ln_b, h2wT, h2_b, h3_w, h3_b, outp);
}